// Round 5
// baseline (6463.264 us; speedup 1.0000x reference)
//
#include <hip/hip_runtime.h>
#include <hip/hip_bf16.h>

#define NT 4           // node types (labels)
#define FEAT 256       // nfeat == nhid
#define OUT3 64        // nclass

typedef __bf16 bf16x8 __attribute__((ext_vector_type(8)));
typedef float  f32x4  __attribute__((ext_vector_type(4)));

__device__ inline unsigned int f2bf_bits(float f) {
    __hip_bfloat16 h = __float2bfloat16(f);   // RNE
    unsigned short u;
    __builtin_memcpy(&u, &h, 2);
    return (unsigned int)u;
}
__device__ inline float bfl(unsigned int u) { return __uint_as_float(u << 16); }
__device__ inline float bfh(unsigned int u) { return __uint_as_float(u & 0xffff0000u); }
// stored feature pos p (pi order) -> natural feature index, within each 64-block
__device__ __host__ inline int nat_of(int p) {
    int lo = p & 63;
    return (p & ~63) | (((lo & 3) << 4) | (lo >> 2));
}

// ---------------- pass A: dst-bucket histogram (dst>>8) + label histogram ----------------
__global__ __launch_bounds__(512) void pass_a(const int* __restrict__ dst,
                                              const int* __restrict__ labels,
                                              int* __restrict__ bcnt, int* __restrict__ lc,
                                              int E, int N) {
    __shared__ int h[256];
    __shared__ int lh[NT];
    int tid = threadIdx.x;
    if (tid < 256) h[tid] = 0;
    if (tid < NT) lh[tid] = 0;
    __syncthreads();
    int base = blockIdx.x * 4096;
#pragma unroll
    for (int k = 0; k < 8; ++k) {
        int e = base + k * 512 + tid;
        if (e < E) atomicAdd(&h[((unsigned)dst[e]) >> 8], 1);
    }
#pragma unroll
    for (int k = 0; k < 8; ++k) {
        int i = base + k * 512 + tid;
        if (i < N) atomicAdd(&lh[labels[i]], 1);
    }
    __syncthreads();
    if (tid < 256) { int v = h[tid]; if (v) atomicAdd(&bcnt[tid], v); }
    if (tid < NT) { int v = lh[tid]; if (v) atomicAdd(&lc[tid], v); }
}

// ------- scan buckets -> boff/gcur; label starts (pad 64) -------
__global__ __launch_bounds__(256) void scan_master(
    const int* __restrict__ bcnt, const int* __restrict__ lc,
    int* __restrict__ boff, int* __restrict__ gcur,
    int* __restrict__ lstart, int NB, int E) {
    __shared__ int s[256];
    int tid = threadIdx.x;
    int own = (tid < NB) ? bcnt[tid] : 0;
    s[tid] = own;
    __syncthreads();
    for (int d = 1; d < 256; d <<= 1) {
        int v = (tid >= d) ? s[tid - d] : 0;
        __syncthreads();
        s[tid] += v;
        __syncthreads();
    }
    int excl = s[tid] - own;
    if (tid < NB) { boff[tid] = excl; gcur[tid] = excl; }
    if (tid == 0) {
        boff[NB] = E;
        int run = 0;
        for (int l = 0; l < NT; ++l) {
            lstart[l] = run;
            run += (lc[l] + 63) & ~63;
        }
    }
}

// ------- node scatter: build iperm (orig -> label-sorted slot) -------
__global__ void scatter_nodes(const int* __restrict__ labels, const int* __restrict__ lstart,
                              int* __restrict__ lcur, int* __restrict__ iperm, int N) {
    int n = blockIdx.x * 256 + threadIdx.x;
    int lab = (n < N) ? labels[n] : -1;
    int lane = threadIdx.x & 63;
    for (int l = 0; l < NT; ++l) {
        unsigned long long m = __ballot(lab == l);
        if (m == 0ull) continue;
        int leader = __builtin_ctzll(m);
        int base = 0;
        if (lane == leader) base = atomicAdd(&lcur[l], (int)__popcll(m));
        base = __shfl(base, leader, 64);
        if (lab == l) {
            int prefix = (int)__popcll(m & ((1ull << lane) - 1ull));
            iperm[n] = lstart[l] + base + prefix;
        }
    }
}

// ================= FUSE_A: scatter_edges + cast_x + cast_w_all =================
// seg 0 [0, nbEB): edge scatter into bucket regions; earr rec: x = slot|(dst&255)<<16, y = w
// seg 1 [nbEB, nbEB+nbX): cast x -> bf16 half-split slot rows
// seg 2 rest: cast W1/W2/W3 -> swizzled bf16 + permuted biases
__global__ __launch_bounds__(512) void fuse_a(
    const int* __restrict__ src, const int* __restrict__ dst, const float* __restrict__ w,
    const int* __restrict__ iperm, int* __restrict__ gcur, uint2* __restrict__ earr, int E,
    const float* __restrict__ x, unsigned short* __restrict__ actLo,
    unsigned short* __restrict__ actHi, int total4,
    const float* __restrict__ W1, const float* __restrict__ W2, const float* __restrict__ W3,
    const float* __restrict__ b1, const float* __restrict__ b2,
    unsigned short* __restrict__ W1b, unsigned short* __restrict__ W2b,
    unsigned short* __restrict__ W3b, float* __restrict__ biasPerm,
    int nbEB, int nbX) {
    int tid = threadIdx.x;
    int blk = (int)blockIdx.x;
    if (blk < nbEB) {
        // ---- edge scatter ----
        __shared__ int h[256];
        __shared__ int basearr[256];
        if (tid < 256) h[tid] = 0;
        __syncthreads();
        int base = blk * 4096;
        int b[8], rank[8], px[8]; float wv[8];
#pragma unroll
        for (int k = 0; k < 8; ++k) {
            int e = base + k * 512 + tid;
            if (e < E) {
                int d = dst[e];
                b[k] = ((unsigned)d) >> 8;
                px[k] = iperm[src[e]] | ((d & 255) << 16);
                wv[k] = w[e];
                rank[k] = atomicAdd(&h[b[k]], 1);
            } else b[k] = -1;
        }
        __syncthreads();
        if (tid < 256) { int c = h[tid]; basearr[tid] = c ? atomicAdd(&gcur[tid], c) : 0; }
        __syncthreads();
#pragma unroll
        for (int k = 0; k < 8; ++k) {
            if (b[k] >= 0) {
                int pos = basearr[b[k]] + rank[k];
                earr[pos] = make_uint2((unsigned)px[k], __float_as_uint(wv[k]));
            }
        }
    } else if (blk < nbEB + nbX) {
        // ---- cast x ----
        int i = (blk - nbEB) * 512 + tid;
        if (i < total4) {
            float4 v = ((const float4*)x)[i];
            unsigned int lo = f2bf_bits(v.x) | (f2bf_bits(v.y) << 16);
            unsigned int hi = f2bf_bits(v.z) | (f2bf_bits(v.w) << 16);
            int slot = iperm[i >> 6];
            unsigned short* dp = ((i & 63) >= 32) ? actHi : actLo;
            ((uint2*)dp)[(size_t)slot * 32 + (i & 31)] = make_uint2(lo, hi);
        }
    } else {
        // ---- cast W + biases ----
        const int S = NT * FEAT * FEAT;
        const int S3 = NT * FEAT * OUT3;
        int idx = (blk - nbEB - nbX) * 512 + tid;
        if (idx < 2 * S + S3) {
            const float* W; unsigned short* D; int OUTF; int t; bool remap;
            if (idx < S)          { W = W1; D = W1b; OUTF = FEAT; t = idx;         remap = false; }
            else if (idx < 2 * S) { W = W2; D = W2b; OUTF = FEAT; t = idx - S;     remap = true; }
            else                  { W = W3; D = W3b; OUTF = OUT3; t = idx - 2 * S; remap = true; }
            int n = t % OUTF;
            int r = t / OUTF;              // lab*256 + k_slot
            int j = r & 7, q = (r >> 3) & 3, k0 = (r >> 5) & 7, lab = r >> 8;
            int k_slot = k0 * 32 + q * 8 + j;
            int k_src = remap ? nat_of(k_slot) : k_slot;
            float f = W[((size_t)(lab * FEAT + k_src)) * OUTF + n];
            D[(((size_t)lab * 8 + k0) * OUTF + n) * 32 + q * 8 + j] = (unsigned short)f2bf_bits(f);
        } else {
            int p2 = idx - (2 * S + S3);
            if (p2 < 256) biasPerm[p2] = b1[nat_of(p2)];
            else if (p2 < 512) biasPerm[p2] = b2[nat_of(p2 - 256)];
        }
    }
}

// ------- bucket sort body (256 thr): counting sort of bucket edges by src>>8 -------
// Output esort: same uint2 records (slot | (dst&255)<<16, w_fp32), src-bucket ordered,
// so the LDS-accumulator agg kernels sweep the sup table in a tight sliding window.
__device__ void bucket_sort_body(int b, const uint2* __restrict__ earr,
                                 const int* __restrict__ boff,
                                 uint2* __restrict__ esort) {
    int s = boff[b], e = boff[b + 1];
    __shared__ int cnt[256], off[256];
    int tid = threadIdx.x;
    cnt[tid] = 0;
    __syncthreads();
    for (int i = s + tid; i < e; i += 256) atomicAdd(&cnt[(earr[i].x & 0xffffu) >> 8], 1);
    __syncthreads();
    off[tid] = cnt[tid];
    __syncthreads();
    for (int d = 1; d < 256; d <<= 1) {
        int v = (tid >= d) ? off[tid - d] : 0;
        __syncthreads();
        off[tid] += v;
        __syncthreads();
    }
    int excl = off[tid] - cnt[tid];
    off[tid] = excl;
    __syncthreads();
    for (int i = s + tid; i < e; i += 256) {
        uint2 r = earr[i];
        int k = atomicAdd(&off[(r.x & 0xffffu) >> 8], 1);
        esort[s + k] = r;
    }
}

// ------- proj 256-out body: dense 64 slots x 256 outs per block, half-split I/O -------
__device__ void proj256_body(int gb,
                             const unsigned short* __restrict__ actLo,
                             const unsigned short* __restrict__ actHi,
                             const unsigned short* __restrict__ Wswz,
                             const int* __restrict__ lstart,
                             unsigned short* __restrict__ supLo,
                             unsigned short* __restrict__ supHi) {
    int warp = threadIdx.x >> 6;
    int lane = threadIdx.x & 63;
    int m0 = gb * 64;
    int lab = (m0 >= lstart[1]) + (m0 >= lstart[2]) + (m0 >= lstart[3]);
    int q = lane >> 4, c = lane & 15;
    int n0 = warp * 64;

    const unsigned short* aLo = actLo + (size_t)(m0 + c) * 128 + q * 8;
    const unsigned short* aHi = actHi + (size_t)(m0 + c) * 128 + q * 8;
    const unsigned short* bb = Wswz + (size_t)lab * FEAT * 256 + (size_t)(n0 + c) * 32 + q * 8;

    f32x4 acc[4][4] = {};
#pragma unroll
    for (int k0 = 0; k0 < 8; ++k0) {
        const unsigned short* abase = (k0 < 4) ? aLo : aHi;
        int koff = (k0 & 3) * 32;
        bf16x8 a[4];
#pragma unroll
        for (int t = 0; t < 4; ++t) a[t] = *(const bf16x8*)(abase + (size_t)t * 2048 + koff);
        const unsigned short* bk = bb + (size_t)k0 * 32 * 256;
#pragma unroll
        for (int u = 0; u < 4; ++u) {
            bf16x8 bfrag = *(const bf16x8*)(bk + u * 512);
#pragma unroll
            for (int t = 0; t < 4; ++t)
                acc[t][u] = __builtin_amdgcn_mfma_f32_16x16x32_bf16(a[t], bfrag, acc[t][u], 0, 0, 0);
        }
    }
    // pi-store: row = m0+t*16+q*4+r ; lane writes p = n0 + c*4 + u -> half n0>>7
    uint2* ov = (uint2*)((n0 >= 128) ? supHi : supLo);
    int cix = ((n0 & 64) >> 2) + c;
#pragma unroll
    for (int t = 0; t < 4; ++t) {
#pragma unroll
        for (int r = 0; r < 4; ++r) {
            int row = m0 + t * 16 + q * 4 + r;
            unsigned int lo = f2bf_bits(acc[t][0][r]) | (f2bf_bits(acc[t][1][r]) << 16);
            unsigned int hi = f2bf_bits(acc[t][2][r]) | (f2bf_bits(acc[t][3][r]) << 16);
            ov[(size_t)row * 32 + cix] = make_uint2(lo, hi);
        }
    }
}

// ================= FUSE_B: src-sort (blocks [0,NB)) + proj256 L1 (rest) =================
__global__ __launch_bounds__(256) void fuse_b(
    const uint2* __restrict__ earr, const int* __restrict__ boff,
    uint2* __restrict__ esort, int NB,
    const unsigned short* __restrict__ actLo, const unsigned short* __restrict__ actHi,
    const unsigned short* __restrict__ Wswz, const int* __restrict__ lstart,
    unsigned short* __restrict__ supLo, unsigned short* __restrict__ supHi) {
    int blk = (int)blockIdx.x;
    if (blk < NB) bucket_sort_body(blk, earr, boff, esort);
    else proj256_body(blk - NB, actLo, actHi, Wswz, lstart, supLo, supHi);
}

// ---------------- standalone proj 256 (layer 2) ----------------
__global__ __launch_bounds__(256) void proj256_kernel(
    const unsigned short* __restrict__ actLo, const unsigned short* __restrict__ actHi,
    const unsigned short* __restrict__ Wswz, const int* __restrict__ lstart,
    unsigned short* __restrict__ supLo, unsigned short* __restrict__ supHi) {
    proj256_body((int)blockIdx.x, actLo, actHi, Wswz, lstart, supLo, supHi);
}

// ---------------- proj 64-out: dense 64 slots x 64 outs per block, half-split input ------
__global__ __launch_bounds__(256) void proj64_kernel(
    const unsigned short* __restrict__ actLo, const unsigned short* __restrict__ actHi,
    const unsigned short* __restrict__ Wswz, const int* __restrict__ lstart,
    unsigned short* __restrict__ outp) {
    int warp = threadIdx.x >> 6;
    int lane = threadIdx.x & 63;
    int m0 = blockIdx.x * 64;
    int lab = (m0 >= lstart[1]) + (m0 >= lstart[2]) + (m0 >= lstart[3]);
    int q = lane >> 4, c = lane & 15;
    int mb = m0 + warp * 16;

    const unsigned short* aLo = actLo + (size_t)(mb + c) * 128 + q * 8;
    const unsigned short* aHi = actHi + (size_t)(mb + c) * 128 + q * 8;
    const unsigned short* bb = Wswz + (size_t)lab * FEAT * OUT3 + (size_t)c * 32 + q * 8;

    f32x4 acc[4] = {};
#pragma unroll
    for (int k0 = 0; k0 < 8; ++k0) {
        const unsigned short* abase = (k0 < 4) ? aLo : aHi;
        bf16x8 a = *(const bf16x8*)(abase + (k0 & 3) * 32);
        const unsigned short* bk = bb + (size_t)k0 * 32 * OUT3;
#pragma unroll
        for (int u = 0; u < 4; ++u) {
            bf16x8 bfrag = *(const bf16x8*)(bk + u * 512);
            acc[u] = __builtin_amdgcn_mfma_f32_16x16x32_bf16(a, bfrag, acc[u], 0, 0, 0);
        }
    }
    uint2* ov = (uint2*)outp;
#pragma unroll
    for (int r = 0; r < 4; ++r) {
        int row = mb + q * 4 + r;
        unsigned int lo = f2bf_bits(acc[0][r]) | (f2bf_bits(acc[1][r]) << 16);
        unsigned int hi = f2bf_bits(acc[2][r]) | (f2bf_bits(acc[3][r]) << 16);
        ov[(size_t)row * 16 + c] = make_uint2(lo, hi);
    }
}

// ------- bucket-resident LDS aggregation, ONE feature half (128 feats) -------
// One 512-thread block per dst bucket (all blocks co-resident). 128KB LDS fp32 acc
// [256 dst][128 feats]. 8 waves walk the bucket's src-sorted edges interleaved; per edge:
// one coalesced 256B gather + 2 LDS float atomics per lane (fire-and-forget, no RMW chain).
// All waves/blocks sweep src in sorted order together -> gathers stay in an L2-resident window.
__global__ __launch_bounds__(512) void aggh_kernel(
    const unsigned int* __restrict__ sup, const uint2* __restrict__ esort,
    const int* __restrict__ boff, const int* __restrict__ iperm,
    const float* __restrict__ biasHalf, unsigned int* __restrict__ outp, int N) {
    __shared__ float acc[256 * 128];   // 128 KB
    int b = blockIdx.x;
    int tid = threadIdx.x;
    int wv = __builtin_amdgcn_readfirstlane((int)(threadIdx.x >> 6));
    int lane = tid & 63;
    float4* az = (float4*)acc;
#pragma unroll
    for (int k = 0; k < 16; ++k) az[k * 512 + tid] = make_float4(0.f, 0.f, 0.f, 0.f);
    __syncthreads();
    int s = __builtin_amdgcn_readfirstlane(boff[b]);
    int e = __builtin_amdgcn_readfirstlane(boff[b + 1]);
    int i = s + wv;
    for (; i + 56 < e; i += 64) {
        uint2 rec[8]; unsigned int v[8];
#pragma unroll
        for (int u = 0; u < 8; ++u) rec[u] = esort[i + 8 * u];
#pragma unroll
        for (int u = 0; u < 8; ++u) v[u] = sup[(size_t)(rec[u].x & 0xffffu) * 64 + lane];
#pragma unroll
        for (int u = 0; u < 8; ++u) {
            float w = __uint_as_float(rec[u].y);
            int row = (rec[u].x >> 16) & 255;
            float* a = acc + row * 128 + lane * 2;
            atomicAdd(a, w * bfl(v[u]));
            atomicAdd(a + 1, w * bfh(v[u]));
        }
    }
    for (; i < e; i += 8) {
        uint2 r = esort[i];
        unsigned int v = sup[(size_t)(r.x & 0xffffu) * 64 + lane];
        float w = __uint_as_float(r.y);
        int row = (r.x >> 16) & 255;
        float* a = acc + row * 128 + lane * 2;
        atomicAdd(a, w * bfl(v));
        atomicAdd(a + 1, w * bfh(v));
    }
    __syncthreads();
    float2 bb = ((const float2*)biasHalf)[lane];
#pragma unroll
    for (int r = 0; r < 32; ++r) {
        int row = wv * 32 + r;
        int node = b * 256 + row;
        if (node < N) {
            int slot = __builtin_amdgcn_readfirstlane(iperm[node]);
            float2 av = *(float2*)(acc + row * 128 + lane * 2);
            float r0 = fmaxf(av.x + bb.x, 0.f);
            float r1 = fmaxf(av.y + bb.y, 0.f);
            outp[(size_t)slot * 64 + lane] = f2bf_bits(r0) | (f2bf_bits(r1) << 16);
        }
    }
}

// ------- bucket-resident LDS aggregation, 64 feats, fp32 out (layer 3) -------
__global__ __launch_bounds__(512) void agg64l_kernel(
    const unsigned short* __restrict__ sup, const uint2* __restrict__ esort,
    const int* __restrict__ boff, const float* __restrict__ b3,
    float* __restrict__ outp, int N) {
    __shared__ float acc[256 * 64];    // 64 KB
    int b = blockIdx.x;
    int tid = threadIdx.x;
    int wv = __builtin_amdgcn_readfirstlane((int)(threadIdx.x >> 6));
    int lane = tid & 63;
    float4* az = (float4*)acc;
#pragma unroll
    for (int k = 0; k < 8; ++k) az[k * 512 + tid] = make_float4(0.f, 0.f, 0.f, 0.f);
    __syncthreads();
    int s = __builtin_amdgcn_readfirstlane(boff[b]);
    int e = __builtin_amdgcn_readfirstlane(boff[b + 1]);
    int i = s + wv;
    for (; i + 56 < e; i += 64) {
        uint2 rec[8]; unsigned short v[8];
#pragma unroll
        for (int u = 0; u < 8; ++u) rec[u] = esort[i + 8 * u];
#pragma unroll
        for (int u = 0; u < 8; ++u) v[u] = sup[(size_t)(rec[u].x & 0xffffu) * 64 + lane];
#pragma unroll
        for (int u = 0; u < 8; ++u) {
            float w = __uint_as_float(rec[u].y);
            int row = (rec[u].x >> 16) & 255;
            atomicAdd(acc + row * 64 + lane, w * __uint_as_float((unsigned int)v[u] << 16));
        }
    }
    for (; i < e; i += 8) {
        uint2 r = esort[i];
        unsigned short v = sup[(size_t)(r.x & 0xffffu) * 64 + lane];
        float w = __uint_as_float(r.y);
        int row = (r.x >> 16) & 255;
        atomicAdd(acc + row * 64 + lane, w * __uint_as_float((unsigned int)v << 16));
    }
    __syncthreads();
    int natp = (((lane & 3) << 4) | (lane >> 2));    // un-permute pi within the 64 outs
    float bias = b3[natp];
#pragma unroll
    for (int r = 0; r < 32; ++r) {
        int row = wv * 32 + r;
        int node = b * 256 + row;
        if (node < N) outp[(size_t)node * 64 + natp] = acc[row * 64 + lane] + bias;
    }
}

extern "C" void kernel_launch(void* const* d_in, const int* in_sizes, int n_in,
                              void* d_out, int out_size, void* d_ws, size_t ws_size,
                              hipStream_t stream) {
    const float* x        = (const float*)d_in[0];
    const int*   edge_src = (const int*)d_in[1];
    const int*   edge_dst = (const int*)d_in[2];
    const float* edge_w   = (const float*)d_in[3];
    const int*   labels   = (const int*)d_in[4];
    const float* W1 = (const float*)d_in[5];
    const float* b1 = (const float*)d_in[6];
    const float* W2 = (const float*)d_in[7];
    const float* b2 = (const float*)d_in[8];
    const float* W3 = (const float*)d_in[9];
    const float* b3 = (const float*)d_in[10];

    const int N = in_sizes[0] / FEAT;
    const int E = in_sizes[1];
    const int NB = (N + 255) >> 8;                    // dst buckets (orig id space)
    const int G64 = (N + NT * 64 + 63) / 64;          // slot-space 64-row tiles (upper bound)
    const int slotCap = G64 * 64;

    // ---- workspace carve (256B aligned) ----
    char* p = (char*)d_ws;
    auto alloc = [&](size_t bytes) -> char* {
        char* r = p;
        p += (bytes + 255) & ~(size_t)255;
        return r;
    };
    unsigned short* bufA = (unsigned short*)alloc((size_t)slotCap * FEAT * 2);
    unsigned short* bufB = (unsigned short*)alloc((size_t)slotCap * FEAT * 2);
    unsigned short* W1b  = (unsigned short*)alloc((size_t)NT * FEAT * FEAT * 2);
    unsigned short* W2b  = (unsigned short*)alloc((size_t)NT * FEAT * FEAT * 2);
    unsigned short* W3b  = (unsigned short*)alloc((size_t)NT * FEAT * OUT3 * 2);
    float*        biasPerm = (float*)alloc(512 * 4);
    uint2*        esort  = (uint2*)alloc((size_t)E * 8);
    int*          iperm  = (int*)alloc((size_t)N * 4);
    int*          counters = (int*)alloc(264 * 4);    // bcnt[256] + lc[4] + lcur[4]
    int*          boff   = (int*)alloc(257 * 4);
    int*          gcur   = (int*)alloc(256 * 4);
    int*          lstart = (int*)alloc(64);
    int* bcnt = counters;
    int* lc   = counters + 256;
    int* lcur = counters + 260;

    // half-table views (lo = feats p<128, hi = p>=128), each slotCap*128 ushorts
    unsigned short* actLo = bufA;
    unsigned short* actHi = bufA + (size_t)slotCap * 128;
    unsigned short* supLo = bufB;
    unsigned short* supHi = bufB + (size_t)slotCap * 128;
    // raw edge staging ALIASED onto d_out (N*OUT3*4 = 12.8MB = E*8; earr is dead after
    // fuse_b's sort, before the final agg64l writes d_out)
    uint2* earr = (uint2*)d_out;

    const int nbEB = (E + 4095) / 4096;
    const int total4 = N * 64;                        // float4 groups in x
    const int nbX = (total4 + 511) / 512;
    const int totW = 2 * NT * FEAT * FEAT + NT * FEAT * OUT3 + 512;
    const int nbW = (totW + 511) / 512;

    // ---- CSR build + label-sort + casts ----
    hipMemsetAsync(counters, 0, 264 * 4, stream);
    pass_a<<<nbEB, 512, 0, stream>>>(edge_dst, labels, bcnt, lc, E, N);
    scan_master<<<1, 256, 0, stream>>>(bcnt, lc, boff, gcur, lstart, NB, E);
    scatter_nodes<<<(N + 255) / 256, 256, 0, stream>>>(labels, lstart, lcur, iperm, N);
    fuse_a<<<nbEB + nbX + nbW, 512, 0, stream>>>(
        edge_src, edge_dst, edge_w, iperm, gcur, earr, E,
        x, actLo, actHi, total4,
        W1, W2, W3, b1, b2, W1b, W2b, W3b, biasPerm, nbEB, nbX);

    // ---- layer 1 (src-sort overlapped with proj256-L1) ----
    fuse_b<<<NB + G64, 256, 0, stream>>>(earr, boff, esort, NB,
                                         actLo, actHi, W1b, lstart, supLo, supHi);
    aggh_kernel<<<NB, 512, 0, stream>>>((const unsigned int*)supLo, esort, boff, iperm,
                                        biasPerm + 0, (unsigned int*)actLo, N);
    aggh_kernel<<<NB, 512, 0, stream>>>((const unsigned int*)supHi, esort, boff, iperm,
                                        biasPerm + 128, (unsigned int*)actHi, N);
    // ---- layer 2 ----
    proj256_kernel<<<G64, 256, 0, stream>>>(actLo, actHi, W2b, lstart, supLo, supHi);
    aggh_kernel<<<NB, 512, 0, stream>>>((const unsigned int*)supLo, esort, boff, iperm,
                                        biasPerm + 256, (unsigned int*)actLo, N);
    aggh_kernel<<<NB, 512, 0, stream>>>((const unsigned int*)supHi, esort, boff, iperm,
                                        biasPerm + 384, (unsigned int*)actHi, N);
    // ---- layer 3 ----
    proj64_kernel<<<G64, 256, 0, stream>>>(actLo, actHi, W3b, lstart, bufB);
    agg64l_kernel<<<NB, 512, 0, stream>>>(bufB, esort, boff, b3, (float*)d_out, N);
}

// Round 6
// 967.914 us; speedup vs baseline: 6.6775x; 6.6775x over previous
//
#include <hip/hip_runtime.h>
#include <hip/hip_bf16.h>

#define NT 4           // node types (labels)
#define FEAT 256       // nfeat == nhid
#define OUT3 64        // nclass
#define NPW 13         // nodes per wave in phased aggregation
#define NS 4           // position slices (~quarter of sup table per slice window)

typedef __bf16 bf16x8 __attribute__((ext_vector_type(8)));
typedef float  f32x4  __attribute__((ext_vector_type(4)));

__device__ inline unsigned int f2bf_bits(float f) {
    __hip_bfloat16 h = __float2bfloat16(f);   // RNE
    unsigned short u;
    __builtin_memcpy(&u, &h, 2);
    return (unsigned int)u;
}
__device__ inline float bfl(unsigned int u) { return __uint_as_float(u << 16); }
__device__ inline float bfh(unsigned int u) { return __uint_as_float(u & 0xffff0000u); }
// stored feature pos p (pi order) -> natural feature index, within each 64-block
__device__ __host__ inline int nat_of(int p) {
    int lo = p & 63;
    return (p & ~63) | (((lo & 3) << 4) | (lo >> 2));
}

// ---------------- pass A: dst-bucket histogram (dst>>8) + label histogram ----------------
__global__ __launch_bounds__(512) void pass_a(const int* __restrict__ dst,
                                              const int* __restrict__ labels,
                                              int* __restrict__ bcnt, int* __restrict__ lc,
                                              int E, int N) {
    __shared__ int h[256];
    __shared__ int lh[NT];
    int tid = threadIdx.x;
    if (tid < 256) h[tid] = 0;
    if (tid < NT) lh[tid] = 0;
    __syncthreads();
    int base = blockIdx.x * 4096;
#pragma unroll
    for (int k = 0; k < 8; ++k) {
        int e = base + k * 512 + tid;
        if (e < E) atomicAdd(&h[((unsigned)dst[e]) >> 8], 1);
    }
#pragma unroll
    for (int k = 0; k < 8; ++k) {
        int i = base + k * 512 + tid;
        if (i < N) atomicAdd(&lh[labels[i]], 1);
    }
    __syncthreads();
    if (tid < 256) { int v = h[tid]; if (v) atomicAdd(&bcnt[tid], v); }
    if (tid < NT) { int v = lh[tid]; if (v) atomicAdd(&lc[tid], v); }
}

// ------- scan buckets -> boff/gcur, rowoff[N]=E; label starts (pad 64) -------
__global__ __launch_bounds__(256) void scan_master(
    const int* __restrict__ bcnt, const int* __restrict__ lc,
    int* __restrict__ boff, int* __restrict__ gcur, int* __restrict__ rowoff,
    int* __restrict__ lstart, int NB, int N, int E) {
    __shared__ int s[256];
    int tid = threadIdx.x;
    int own = (tid < NB) ? bcnt[tid] : 0;
    s[tid] = own;
    __syncthreads();
    for (int d = 1; d < 256; d <<= 1) {
        int v = (tid >= d) ? s[tid - d] : 0;
        __syncthreads();
        s[tid] += v;
        __syncthreads();
    }
    int excl = s[tid] - own;
    if (tid < NB) { boff[tid] = excl; gcur[tid] = excl; }
    if (tid == 0) {
        boff[NB] = E; rowoff[N] = E;
        int run = 0;
        for (int l = 0; l < NT; ++l) {
            lstart[l] = run;
            run += (lc[l] + 63) & ~63;
        }
    }
}

// ------- node scatter: build iperm (orig -> label-sorted slot) -------
__global__ void scatter_nodes(const int* __restrict__ labels, const int* __restrict__ lstart,
                              int* __restrict__ lcur, int* __restrict__ iperm, int N) {
    int n = blockIdx.x * 256 + threadIdx.x;
    int lab = (n < N) ? labels[n] : -1;
    int lane = threadIdx.x & 63;
    for (int l = 0; l < NT; ++l) {
        unsigned long long m = __ballot(lab == l);
        if (m == 0ull) continue;
        int leader = __builtin_ctzll(m);
        int base = 0;
        if (lane == leader) base = atomicAdd(&lcur[l], (int)__popcll(m));
        base = __shfl(base, leader, 64);
        if (lab == l) {
            int prefix = (int)__popcll(m & ((1ull << lane) - 1ull));
            iperm[n] = lstart[l] + base + prefix;
        }
    }
}

// ================= FUSE_A: scatter_edges + cast_x + cast_w_all =================
// seg 0 [0, nbEB): edge scatter into bucket regions; earr rec: x = slot|(dst&255)<<16, y = w
// seg 1 [nbEB, nbEB+nbX): cast x -> bf16 half-split slot rows
// seg 2 rest: cast W1/W2/W3 -> swizzled bf16 + permuted biases
__global__ __launch_bounds__(512) void fuse_a(
    const int* __restrict__ src, const int* __restrict__ dst, const float* __restrict__ w,
    const int* __restrict__ iperm, int* __restrict__ gcur, uint2* __restrict__ earr, int E,
    const float* __restrict__ x, unsigned short* __restrict__ actLo,
    unsigned short* __restrict__ actHi, int total4,
    const float* __restrict__ W1, const float* __restrict__ W2, const float* __restrict__ W3,
    const float* __restrict__ b1, const float* __restrict__ b2,
    unsigned short* __restrict__ W1b, unsigned short* __restrict__ W2b,
    unsigned short* __restrict__ W3b, float* __restrict__ biasPerm,
    int nbEB, int nbX) {
    int tid = threadIdx.x;
    int blk = (int)blockIdx.x;
    if (blk < nbEB) {
        // ---- edge scatter ----
        __shared__ int h[256];
        __shared__ int basearr[256];
        if (tid < 256) h[tid] = 0;
        __syncthreads();
        int base = blk * 4096;
        int b[8], rank[8], px[8]; float wv[8];
#pragma unroll
        for (int k = 0; k < 8; ++k) {
            int e = base + k * 512 + tid;
            if (e < E) {
                int d = dst[e];
                b[k] = ((unsigned)d) >> 8;
                px[k] = iperm[src[e]] | ((d & 255) << 16);
                wv[k] = w[e];
                rank[k] = atomicAdd(&h[b[k]], 1);
            } else b[k] = -1;
        }
        __syncthreads();
        if (tid < 256) { int c = h[tid]; basearr[tid] = c ? atomicAdd(&gcur[tid], c) : 0; }
        __syncthreads();
#pragma unroll
        for (int k = 0; k < 8; ++k) {
            if (b[k] >= 0) {
                int pos = basearr[b[k]] + rank[k];
                earr[pos] = make_uint2((unsigned)px[k], __float_as_uint(wv[k]));
            }
        }
    } else if (blk < nbEB + nbX) {
        // ---- cast x ----
        int i = (blk - nbEB) * 512 + tid;
        if (i < total4) {
            float4 v = ((const float4*)x)[i];
            unsigned int lo = f2bf_bits(v.x) | (f2bf_bits(v.y) << 16);
            unsigned int hi = f2bf_bits(v.z) | (f2bf_bits(v.w) << 16);
            int slot = iperm[i >> 6];
            unsigned short* dp = ((i & 63) >= 32) ? actHi : actLo;
            ((uint2*)dp)[(size_t)slot * 32 + (i & 31)] = make_uint2(lo, hi);
        }
    } else {
        // ---- cast W + biases ----
        const int S = NT * FEAT * FEAT;
        const int S3 = NT * FEAT * OUT3;
        int idx = (blk - nbEB - nbX) * 512 + tid;
        if (idx < 2 * S + S3) {
            const float* W; unsigned short* D; int OUTF; int t; bool remap;
            if (idx < S)          { W = W1; D = W1b; OUTF = FEAT; t = idx;         remap = false; }
            else if (idx < 2 * S) { W = W2; D = W2b; OUTF = FEAT; t = idx - S;     remap = true; }
            else                  { W = W3; D = W3b; OUTF = OUT3; t = idx - 2 * S; remap = true; }
            int n = t % OUTF;
            int r = t / OUTF;              // lab*256 + k_slot
            int j = r & 7, q = (r >> 3) & 3, k0 = (r >> 5) & 7, lab = r >> 8;
            int k_slot = k0 * 32 + q * 8 + j;
            int k_src = remap ? nat_of(k_slot) : k_slot;
            float f = W[((size_t)(lab * FEAT + k_src)) * OUTF + n];
            D[(((size_t)lab * 8 + k0) * OUTF + n) * 32 + q * 8 + j] = (unsigned short)f2bf_bits(f);
        } else {
            int p2 = idx - (2 * S + S3);
            if (p2 < 256) biasPerm[p2] = b1[nat_of(p2)];
            else if (p2 < 512) biasPerm[p2] = b2[nat_of(p2 - 256)];
        }
    }
}

// ------- bucket sort body (256 thr): within-bucket counting sort -> rowoff + edata -------
// final record: (w_bf16 << 16) | src_slot; rows then sorted ascending by src_slot so the
// phased aggregation's position slices map to src-slot quantiles.
__device__ void bucket_sort_body(int b, const uint2* __restrict__ earr,
                                 const int* __restrict__ boff, int* __restrict__ rowoff,
                                 unsigned int* __restrict__ edata, int N) {
    int s = boff[b], e = boff[b + 1];
    __shared__ int cnt[256], off[256];
    int tid = threadIdx.x;
    cnt[tid] = 0;
    __syncthreads();
    for (int i = s + tid; i < e; i += 256) atomicAdd(&cnt[(earr[i].x >> 16) & 255], 1);
    __syncthreads();
    off[tid] = cnt[tid];
    __syncthreads();
    for (int d = 1; d < 256; d <<= 1) {
        int v = (tid >= d) ? off[tid - d] : 0;
        __syncthreads();
        off[tid] += v;
        __syncthreads();
    }
    int excl = off[tid] - cnt[tid];
    int node = b * 256 + tid;
    if (node < N) rowoff[node] = s + excl;
    int rs = s + excl;                 // this thread's row start
    off[tid] = excl;
    __syncthreads();
    for (int i = s + tid; i < e; i += 256) {
        uint2 r = earr[i];
        int d = (r.x >> 16) & 255;
        int k = atomicAdd(&off[d], 1);
        edata[s + k] = (f2bf_bits(__uint_as_float(r.y)) << 16) | (r.x & 0xffff);
    }
    __syncthreads();
    // ---- within-row insertion sort by src slot (rows avg ~32) ----
    int re = s + off[tid];             // off advanced to excl+cnt = row end
    for (int i = rs + 1; i < re; ++i) {
        unsigned int key = edata[i];
        unsigned int ks = key & 0xffffu;
        int k = i - 1;
        while (k >= rs && (edata[k] & 0xffffu) > ks) { edata[k + 1] = edata[k]; --k; }
        edata[k + 1] = key;
    }
}

// ------- proj 256-out body: dense 64 slots x 256 outs per block, half-split I/O -------
__device__ void proj256_body(int gb,
                             const unsigned short* __restrict__ actLo,
                             const unsigned short* __restrict__ actHi,
                             const unsigned short* __restrict__ Wswz,
                             const int* __restrict__ lstart,
                             unsigned short* __restrict__ supLo,
                             unsigned short* __restrict__ supHi) {
    int warp = threadIdx.x >> 6;
    int lane = threadIdx.x & 63;
    int m0 = gb * 64;
    int lab = (m0 >= lstart[1]) + (m0 >= lstart[2]) + (m0 >= lstart[3]);
    int q = lane >> 4, c = lane & 15;
    int n0 = warp * 64;

    const unsigned short* aLo = actLo + (size_t)(m0 + c) * 128 + q * 8;
    const unsigned short* aHi = actHi + (size_t)(m0 + c) * 128 + q * 8;
    const unsigned short* bb = Wswz + (size_t)lab * FEAT * 256 + (size_t)(n0 + c) * 32 + q * 8;

    f32x4 acc[4][4] = {};
#pragma unroll
    for (int k0 = 0; k0 < 8; ++k0) {
        const unsigned short* abase = (k0 < 4) ? aLo : aHi;
        int koff = (k0 & 3) * 32;
        bf16x8 a[4];
#pragma unroll
        for (int t = 0; t < 4; ++t) a[t] = *(const bf16x8*)(abase + (size_t)t * 2048 + koff);
        const unsigned short* bk = bb + (size_t)k0 * 32 * 256;
#pragma unroll
        for (int u = 0; u < 4; ++u) {
            bf16x8 bfrag = *(const bf16x8*)(bk + u * 512);
#pragma unroll
            for (int t = 0; t < 4; ++t)
                acc[t][u] = __builtin_amdgcn_mfma_f32_16x16x32_bf16(a[t], bfrag, acc[t][u], 0, 0, 0);
        }
    }
    // pi-store: row = m0+t*16+q*4+r ; lane writes p = n0 + c*4 + u -> half n0>>7
    uint2* ov = (uint2*)((n0 >= 128) ? supHi : supLo);
    int cix = ((n0 & 64) >> 2) + c;
#pragma unroll
    for (int t = 0; t < 4; ++t) {
#pragma unroll
        for (int r = 0; r < 4; ++r) {
            int row = m0 + t * 16 + q * 4 + r;
            unsigned int lo = f2bf_bits(acc[t][0][r]) | (f2bf_bits(acc[t][1][r]) << 16);
            unsigned int hi = f2bf_bits(acc[t][2][r]) | (f2bf_bits(acc[t][3][r]) << 16);
            ov[(size_t)row * 32 + cix] = make_uint2(lo, hi);
        }
    }
}

// ================= FUSE_B: bucket_sort (blocks [0,NB)) + proj256 L1 (rest) =================
__global__ __launch_bounds__(256) void fuse_b(
    const uint2* __restrict__ earr, const int* __restrict__ boff,
    int* __restrict__ rowoff, unsigned int* __restrict__ edata, int N, int NB,
    const unsigned short* __restrict__ actLo, const unsigned short* __restrict__ actHi,
    const unsigned short* __restrict__ Wswz, const int* __restrict__ lstart,
    unsigned short* __restrict__ supLo, unsigned short* __restrict__ supHi) {
    int blk = (int)blockIdx.x;
    if (blk < NB) bucket_sort_body(blk, earr, boff, rowoff, edata, N);
    else proj256_body(blk - NB, actLo, actHi, Wswz, lstart, supLo, supHi);
}

// ---------------- standalone proj 256 (layer 2) ----------------
__global__ __launch_bounds__(256) void proj256_kernel(
    const unsigned short* __restrict__ actLo, const unsigned short* __restrict__ actHi,
    const unsigned short* __restrict__ Wswz, const int* __restrict__ lstart,
    unsigned short* __restrict__ supLo, unsigned short* __restrict__ supHi) {
    proj256_body((int)blockIdx.x, actLo, actHi, Wswz, lstart, supLo, supHi);
}

// ---------------- proj 64-out: dense 64 slots x 64 outs per block, half-split input ------
__global__ __launch_bounds__(256) void proj64_kernel(
    const unsigned short* __restrict__ actLo, const unsigned short* __restrict__ actHi,
    const unsigned short* __restrict__ Wswz, const int* __restrict__ lstart,
    unsigned short* __restrict__ outp) {
    int warp = threadIdx.x >> 6;
    int lane = threadIdx.x & 63;
    int m0 = blockIdx.x * 64;
    int lab = (m0 >= lstart[1]) + (m0 >= lstart[2]) + (m0 >= lstart[3]);
    int q = lane >> 4, c = lane & 15;
    int mb = m0 + warp * 16;

    const unsigned short* aLo = actLo + (size_t)(mb + c) * 128 + q * 8;
    const unsigned short* aHi = actHi + (size_t)(mb + c) * 128 + q * 8;
    const unsigned short* bb = Wswz + (size_t)lab * FEAT * OUT3 + (size_t)c * 32 + q * 8;

    f32x4 acc[4] = {};
#pragma unroll
    for (int k0 = 0; k0 < 8; ++k0) {
        const unsigned short* abase = (k0 < 4) ? aLo : aHi;
        bf16x8 a = *(const bf16x8*)(abase + (k0 & 3) * 32);
        const unsigned short* bk = bb + (size_t)k0 * 32 * OUT3;
#pragma unroll
        for (int u = 0; u < 4; ++u) {
            bf16x8 bfrag = *(const bf16x8*)(bk + u * 512);
            acc[u] = __builtin_amdgcn_mfma_f32_16x16x32_bf16(a, bfrag, acc[u], 0, 0, 0);
        }
    }
    uint2* ov = (uint2*)outp;
#pragma unroll
    for (int r = 0; r < 4; ++r) {
        int row = mb + q * 4 + r;
        unsigned int lo = f2bf_bits(acc[0][r]) | (f2bf_bits(acc[1][r]) << 16);
        unsigned int hi = f2bf_bits(acc[2][r]) | (f2bf_bits(acc[3][r]) << 16);
        ov[(size_t)row * 16 + c] = make_uint2(lo, hi);
    }
}

// ------- PHASED aggregation over ONE feature half (128 feats) -------
// All-resident grid (4 waves/block, NPW nodes/wave). Rows are src-sorted, so position
// slice sl of each row ~ src-slot quantile band sl/NS..(sl+1)/NS: all resident waves
// sweep the sup table together in NS windows of ~table/NS (<= per-XCD L2). Batched
// register gathers (4 in flight/wave), no atomics, no per-edge scalar ops.
__global__ __launch_bounds__(256, 4) void agg256hp_kernel(
    const unsigned int* __restrict__ sup, const int* __restrict__ rowoff,
    const unsigned int* __restrict__ edata, const int* __restrict__ iperm,
    const float* __restrict__ biasHalf, unsigned int* __restrict__ outp, int N) {
    int wid = (int)blockIdx.x * 4 + (int)(threadIdx.x >> 6);
    int lane = threadIdx.x & 63;
    int n0 = wid * NPW;
    if (n0 >= N) return;
    int base[NPW], len[NPW];
    float a0[NPW], a1[NPW];
#pragma unroll
    for (int t = 0; t < NPW; ++t) {
        int n = n0 + t;
        int s = (n < N) ? __builtin_amdgcn_readfirstlane(rowoff[n]) : 0;
        int e = (n < N) ? __builtin_amdgcn_readfirstlane(rowoff[n + 1]) : 0;
        base[t] = s; len[t] = e - s;
        a0[t] = 0.f; a1[t] = 0.f;
    }
#pragma unroll
    for (int sl = 0; sl < NS; ++sl) {
#pragma unroll
        for (int t = 0; t < NPW; ++t) {
            int j  = base[t] + ((len[t] * sl) >> 2);
            int j1 = base[t] + ((len[t] * (sl + 1)) >> 2);
            float aa0 = a0[t], aa1 = a1[t];
            for (; j + 4 <= j1; j += 4) {
                unsigned int e0 = edata[j],     e1 = edata[j + 1];
                unsigned int e2 = edata[j + 2], e3 = edata[j + 3];
                unsigned int v0 = sup[(size_t)(e0 & 0xffff) * 64 + lane];
                unsigned int v1 = sup[(size_t)(e1 & 0xffff) * 64 + lane];
                unsigned int v2 = sup[(size_t)(e2 & 0xffff) * 64 + lane];
                unsigned int v3 = sup[(size_t)(e3 & 0xffff) * 64 + lane];
                float w0 = __uint_as_float(e0 & 0xffff0000u);
                float w1 = __uint_as_float(e1 & 0xffff0000u);
                float w2 = __uint_as_float(e2 & 0xffff0000u);
                float w3 = __uint_as_float(e3 & 0xffff0000u);
                aa0 += w0 * bfl(v0); aa1 += w0 * bfh(v0);
                aa0 += w1 * bfl(v1); aa1 += w1 * bfh(v1);
                aa0 += w2 * bfl(v2); aa1 += w2 * bfh(v2);
                aa0 += w3 * bfl(v3); aa1 += w3 * bfh(v3);
            }
            for (; j < j1; ++j) {
                unsigned int ed = edata[j];
                unsigned int v = sup[(size_t)(ed & 0xffff) * 64 + lane];
                float w = __uint_as_float(ed & 0xffff0000u);
                aa0 += w * bfl(v); aa1 += w * bfh(v);
            }
            a0[t] = aa0; a1[t] = aa1;
        }
    }
    float2 b = ((const float2*)biasHalf)[lane];
#pragma unroll
    for (int t = 0; t < NPW; ++t) {
        int n = n0 + t;
        if (n < N) {
            int slot = __builtin_amdgcn_readfirstlane(iperm[n]);
            float r0 = fmaxf(a0[t] + b.x, 0.f);
            float r1 = fmaxf(a1[t] + b.y, 0.f);
            unsigned int o = f2bf_bits(r0) | (f2bf_bits(r1) << 16);
            // output never re-read here: nontemporal keeps the gather window in L2
            __builtin_nontemporal_store(o, &outp[(size_t)slot * 64 + lane]);
        }
    }
}

// ---------------- aggregation, 64-feat: one wave per node (lane = stored pos), fp32 out --
__global__ __launch_bounds__(256) void agg64_kernel(
    const unsigned short* __restrict__ sup, const int* __restrict__ rowoff,
    const unsigned int* __restrict__ edata, const float* __restrict__ b3,
    float* __restrict__ outp, int N) {
    int warp = __builtin_amdgcn_readfirstlane((int)(threadIdx.x >> 6));
    int node = (int)blockIdx.x * 4 + warp;
    if (node >= N) return;
    int lane = threadIdx.x & 63;
    int s = __builtin_amdgcn_readfirstlane(rowoff[node]);
    int e = __builtin_amdgcn_readfirstlane(rowoff[node + 1]);
    float a = 0.f;
    int j = s;
    for (; j + 16 <= e; j += 16) {
        unsigned int ed[16]; unsigned short v[16];
#pragma unroll
        for (int u = 0; u < 16; ++u) ed[u] = edata[j + u];
#pragma unroll
        for (int u = 0; u < 16; ++u) v[u] = sup[(size_t)(ed[u] & 0xffff) * 64 + lane];
#pragma unroll
        for (int u = 0; u < 16; ++u)
            a += __uint_as_float(ed[u] & 0xffff0000u) * __uint_as_float((unsigned int)v[u] << 16);
    }
    if (j < e) {
        unsigned int ed[16]; float wm[16]; unsigned short v[16];
#pragma unroll
        for (int u = 0; u < 16; ++u) {
            int jj = j + u;
            int jc = (jj < e) ? jj : e - 1;
            ed[u] = edata[jc];
            wm[u] = (jj < e) ? __uint_as_float(ed[u] & 0xffff0000u) : 0.f;
        }
#pragma unroll
        for (int u = 0; u < 16; ++u) v[u] = sup[(size_t)(ed[u] & 0xffff) * 64 + lane];
#pragma unroll
        for (int u = 0; u < 16; ++u)
            a += wm[u] * __uint_as_float((unsigned int)v[u] << 16);
    }
    int natp = (((lane & 3) << 4) | (lane >> 2));    // un-permute pi within the 64 outs
    outp[(size_t)node * 64 + natp] = a + b3[natp];
}

extern "C" void kernel_launch(void* const* d_in, const int* in_sizes, int n_in,
                              void* d_out, int out_size, void* d_ws, size_t ws_size,
                              hipStream_t stream) {
    const float* x        = (const float*)d_in[0];
    const int*   edge_src = (const int*)d_in[1];
    const int*   edge_dst = (const int*)d_in[2];
    const float* edge_w   = (const float*)d_in[3];
    const int*   labels   = (const int*)d_in[4];
    const float* W1 = (const float*)d_in[5];
    const float* b1 = (const float*)d_in[6];
    const float* W2 = (const float*)d_in[7];
    const float* b2 = (const float*)d_in[8];
    const float* W3 = (const float*)d_in[9];
    const float* b3 = (const float*)d_in[10];

    const int N = in_sizes[0] / FEAT;
    const int E = in_sizes[1];
    const int NB = (N + 255) >> 8;                    // dst buckets (orig id space)
    const int G64 = (N + NT * 64 + 63) / 64;          // slot-space 64-row tiles (upper bound)
    const int slotCap = G64 * 64;

    // ---- workspace carve (256B aligned) ----
    char* p = (char*)d_ws;
    auto alloc = [&](size_t bytes) -> char* {
        char* r = p;
        p += (bytes + 255) & ~(size_t)255;
        return r;
    };
    unsigned short* bufA = (unsigned short*)alloc((size_t)slotCap * FEAT * 2);
    unsigned short* bufB = (unsigned short*)alloc((size_t)slotCap * FEAT * 2);
    unsigned short* W1b  = (unsigned short*)alloc((size_t)NT * FEAT * FEAT * 2);
    unsigned short* W2b  = (unsigned short*)alloc((size_t)NT * FEAT * FEAT * 2);
    unsigned short* W3b  = (unsigned short*)alloc((size_t)NT * FEAT * OUT3 * 2);
    float*        biasPerm = (float*)alloc(512 * 4);
    int*          rowoff = (int*)alloc((size_t)(N + 1) * 4);
    unsigned int* edata  = (unsigned int*)alloc((size_t)E * 4);
    int*          iperm  = (int*)alloc((size_t)N * 4);
    int*          counters = (int*)alloc(264 * 4);    // bcnt[256] + lc[4] + lcur[4]
    int*          boff   = (int*)alloc(257 * 4);
    int*          gcur   = (int*)alloc(256 * 4);
    int*          lstart = (int*)alloc(64);
    int* bcnt = counters;
    int* lc   = counters + 256;
    int* lcur = counters + 260;

    // half-table views (lo = feats p<128, hi = p>=128), each slotCap*128 ushorts
    unsigned short* actLo = bufA;
    unsigned short* actHi = bufA + (size_t)slotCap * 128;
    unsigned short* supLo = bufB;
    unsigned short* supHi = bufB + (size_t)slotCap * 128;
    // bucket-sort staging ALIASED onto d_out (N*OUT3*4 = 12.8MB = E*8; d_out written
    // only by the final agg64, and earr is fully overwritten by scatter before reads)
    uint2* earr = (uint2*)d_out;

    const int nbEB = (E + 4095) / 4096;
    const int total4 = N * 64;                        // float4 groups in x
    const int nbX = (total4 + 511) / 512;
    const int totW = 2 * NT * FEAT * FEAT + NT * FEAT * OUT3 + 512;
    const int nbW = (totW + 511) / 512;

    // ---- CSR build + label-sort + casts ----
    hipMemsetAsync(counters, 0, 264 * 4, stream);
    pass_a<<<nbEB, 512, 0, stream>>>(edge_dst, labels, bcnt, lc, E, N);
    scan_master<<<1, 256, 0, stream>>>(bcnt, lc, boff, gcur, rowoff, lstart, NB, N, E);
    scatter_nodes<<<(N + 255) / 256, 256, 0, stream>>>(labels, lstart, lcur, iperm, N);
    fuse_a<<<nbEB + nbX + nbW, 512, 0, stream>>>(
        edge_src, edge_dst, edge_w, iperm, gcur, earr, E,
        x, actLo, actHi, total4,
        W1, W2, W3, b1, b2, W1b, W2b, W3b, biasPerm, nbEB, nbX);

    const int gridP = (N + 4 * NPW - 1) / (4 * NPW);  // all-resident phased-agg grid
    const int aggGrid = (N + 3) / 4;
    // ---- layer 1 (bucket_sort+src-sort overlapped with proj256-L1) ----
    fuse_b<<<NB + G64, 256, 0, stream>>>(earr, boff, rowoff, edata, N, NB,
                                         actLo, actHi, W1b, lstart, supLo, supHi);
    agg256hp_kernel<<<gridP, 256, 0, stream>>>((const unsigned int*)supLo, rowoff, edata, iperm,
                                               biasPerm + 0, (unsigned int*)actLo, N);
    agg256hp_kernel<<<gridP, 256, 0, stream>>>((const unsigned int*)supHi, rowoff, edata, iperm,
                                               biasPerm + 128, (unsigned int*)actHi, N);
    // ---- layer 2 ----
    proj256_kernel<<<G64, 256, 0, stream>>>(actLo, actHi, W2b, lstart, supLo, supHi);
    agg256hp_kernel<<<gridP, 256, 0, stream>>>((const unsigned int*)supLo, rowoff, edata, iperm,
                                               biasPerm + 256, (unsigned int*)actLo, N);
    agg256hp_kernel<<<gridP, 256, 0, stream>>>((const unsigned int*)supHi, rowoff, edata, iperm,
                                               biasPerm + 384, (unsigned int*)actHi, N);
    // ---- layer 3 ----
    proj64_kernel<<<G64, 256, 0, stream>>>(actLo, actHi, W3b, lstart, bufB);
    agg64_kernel<<<aggGrid, 256, 0, stream>>>(bufB, rowoff, edata, b3, (float*)d_out, N);
}

// Round 7
// 767.710 us; speedup vs baseline: 8.4189x; 1.2608x over previous
//
#include <hip/hip_runtime.h>
#include <hip/hip_bf16.h>

#define NT 4           // node types (labels)
#define FEAT 256       // nfeat == nhid
#define OUT3 64        // nclass
#define NPW 13         // nodes (row cursors) per wave in banded aggregation
#define NBAND 8        // src-slot bands (slot>>13), window = 8192 rows

typedef __bf16 bf16x8 __attribute__((ext_vector_type(8)));
typedef float  f32x4  __attribute__((ext_vector_type(4)));

__device__ inline unsigned int f2bf_bits(float f) {
    __hip_bfloat16 h = __float2bfloat16(f);   // RNE
    unsigned short u;
    __builtin_memcpy(&u, &h, 2);
    return (unsigned int)u;
}
__device__ inline float bfl(unsigned int u) { return __uint_as_float(u << 16); }
__device__ inline float bfh(unsigned int u) { return __uint_as_float(u & 0xffff0000u); }
// stored feature pos p (pi order) -> natural feature index, within each 64-block
__device__ __host__ inline int nat_of(int p) {
    int lo = p & 63;
    return (p & ~63) | (((lo & 3) << 4) | (lo >> 2));
}

// ---------------- pass A: dst-bucket histogram (dst>>8) + label histogram ----------------
__global__ __launch_bounds__(512) void pass_a(const int* __restrict__ dst,
                                              const int* __restrict__ labels,
                                              int* __restrict__ bcnt, int* __restrict__ lc,
                                              int E, int N) {
    __shared__ int h[256];
    __shared__ int lh[NT];
    int tid = threadIdx.x;
    if (tid < 256) h[tid] = 0;
    if (tid < NT) lh[tid] = 0;
    __syncthreads();
    int base = blockIdx.x * 4096;
#pragma unroll
    for (int k = 0; k < 8; ++k) {
        int e = base + k * 512 + tid;
        if (e < E) atomicAdd(&h[((unsigned)dst[e]) >> 8], 1);
    }
#pragma unroll
    for (int k = 0; k < 8; ++k) {
        int i = base + k * 512 + tid;
        if (i < N) atomicAdd(&lh[labels[i]], 1);
    }
    __syncthreads();
    if (tid < 256) { int v = h[tid]; if (v) atomicAdd(&bcnt[tid], v); }
    if (tid < NT) { int v = lh[tid]; if (v) atomicAdd(&lc[tid], v); }
}

// ------- scan buckets -> boff/gcur, rb[8N]=E; label starts (pad 64) -------
__global__ __launch_bounds__(256) void scan_master(
    const int* __restrict__ bcnt, const int* __restrict__ lc,
    int* __restrict__ boff, int* __restrict__ gcur, int* __restrict__ rb,
    int* __restrict__ lstart, int NB, int N, int E) {
    __shared__ int s[256];
    int tid = threadIdx.x;
    int own = (tid < NB) ? bcnt[tid] : 0;
    s[tid] = own;
    __syncthreads();
    for (int d = 1; d < 256; d <<= 1) {
        int v = (tid >= d) ? s[tid - d] : 0;
        __syncthreads();
        s[tid] += v;
        __syncthreads();
    }
    int excl = s[tid] - own;
    if (tid < NB) { boff[tid] = excl; gcur[tid] = excl; }
    if (tid == 0) {
        boff[NB] = E; rb[(size_t)N * NBAND] = E;
        int run = 0;
        for (int l = 0; l < NT; ++l) {
            lstart[l] = run;
            run += (lc[l] + 63) & ~63;
        }
    }
}

// ------- node scatter: build iperm (orig -> label-sorted slot) -------
__global__ void scatter_nodes(const int* __restrict__ labels, const int* __restrict__ lstart,
                              int* __restrict__ lcur, int* __restrict__ iperm, int N) {
    int n = blockIdx.x * 256 + threadIdx.x;
    int lab = (n < N) ? labels[n] : -1;
    int lane = threadIdx.x & 63;
    for (int l = 0; l < NT; ++l) {
        unsigned long long m = __ballot(lab == l);
        if (m == 0ull) continue;
        int leader = __builtin_ctzll(m);
        int base = 0;
        if (lane == leader) base = atomicAdd(&lcur[l], (int)__popcll(m));
        base = __shfl(base, leader, 64);
        if (lab == l) {
            int prefix = (int)__popcll(m & ((1ull << lane) - 1ull));
            iperm[n] = lstart[l] + base + prefix;
        }
    }
}

// ================= FUSE_A: scatter_edges + cast_x + cast_w_all =================
// seg 0 [0, nbEB): edge scatter into bucket regions; earr rec: x = slot|(dst&255)<<16, y = w
// seg 1 [nbEB, nbEB+nbX): cast x -> bf16 half-split slot rows
// seg 2 rest: cast W1/W2/W3 -> swizzled bf16 + permuted biases
__global__ __launch_bounds__(512) void fuse_a(
    const int* __restrict__ src, const int* __restrict__ dst, const float* __restrict__ w,
    const int* __restrict__ iperm, int* __restrict__ gcur, uint2* __restrict__ earr, int E,
    const float* __restrict__ x, unsigned short* __restrict__ actLo,
    unsigned short* __restrict__ actHi, int total4,
    const float* __restrict__ W1, const float* __restrict__ W2, const float* __restrict__ W3,
    const float* __restrict__ b1, const float* __restrict__ b2,
    unsigned short* __restrict__ W1b, unsigned short* __restrict__ W2b,
    unsigned short* __restrict__ W3b, float* __restrict__ biasPerm,
    int nbEB, int nbX) {
    int tid = threadIdx.x;
    int blk = (int)blockIdx.x;
    if (blk < nbEB) {
        // ---- edge scatter ----
        __shared__ int h[256];
        __shared__ int basearr[256];
        if (tid < 256) h[tid] = 0;
        __syncthreads();
        int base = blk * 4096;
        int b[8], rank[8], px[8]; float wv[8];
#pragma unroll
        for (int k = 0; k < 8; ++k) {
            int e = base + k * 512 + tid;
            if (e < E) {
                int d = dst[e];
                b[k] = ((unsigned)d) >> 8;
                px[k] = iperm[src[e]] | ((d & 255) << 16);
                wv[k] = w[e];
                rank[k] = atomicAdd(&h[b[k]], 1);
            } else b[k] = -1;
        }
        __syncthreads();
        if (tid < 256) { int c = h[tid]; basearr[tid] = c ? atomicAdd(&gcur[tid], c) : 0; }
        __syncthreads();
#pragma unroll
        for (int k = 0; k < 8; ++k) {
            if (b[k] >= 0) {
                int pos = basearr[b[k]] + rank[k];
                earr[pos] = make_uint2((unsigned)px[k], __float_as_uint(wv[k]));
            }
        }
    } else if (blk < nbEB + nbX) {
        // ---- cast x ----
        int i = (blk - nbEB) * 512 + tid;
        if (i < total4) {
            float4 v = ((const float4*)x)[i];
            unsigned int lo = f2bf_bits(v.x) | (f2bf_bits(v.y) << 16);
            unsigned int hi = f2bf_bits(v.z) | (f2bf_bits(v.w) << 16);
            int slot = iperm[i >> 6];
            unsigned short* dp = ((i & 63) >= 32) ? actHi : actLo;
            ((uint2*)dp)[(size_t)slot * 32 + (i & 31)] = make_uint2(lo, hi);
        }
    } else {
        // ---- cast W + biases ----
        const int S = NT * FEAT * FEAT;
        const int S3 = NT * FEAT * OUT3;
        int idx = (blk - nbEB - nbX) * 512 + tid;
        if (idx < 2 * S + S3) {
            const float* W; unsigned short* D; int OUTF; int t; bool remap;
            if (idx < S)          { W = W1; D = W1b; OUTF = FEAT; t = idx;         remap = false; }
            else if (idx < 2 * S) { W = W2; D = W2b; OUTF = FEAT; t = idx - S;     remap = true; }
            else                  { W = W3; D = W3b; OUTF = OUT3; t = idx - 2 * S; remap = true; }
            int n = t % OUTF;
            int r = t / OUTF;              // lab*256 + k_slot
            int j = r & 7, q = (r >> 3) & 3, k0 = (r >> 5) & 7, lab = r >> 8;
            int k_slot = k0 * 32 + q * 8 + j;
            int k_src = remap ? nat_of(k_slot) : k_slot;
            float f = W[((size_t)(lab * FEAT + k_src)) * OUTF + n];
            D[(((size_t)lab * 8 + k0) * OUTF + n) * 32 + q * 8 + j] = (unsigned short)f2bf_bits(f);
        } else {
            int p2 = idx - (2 * S + S3);
            if (p2 < 256) biasPerm[p2] = b1[nat_of(p2)];
            else if (p2 < 512) biasPerm[p2] = b2[nat_of(p2 - 256)];
        }
    }
}

// ------- bucket sort body (256 thr): 2048-bin counting sort by (dst_low8, src_band3) -----
// final record: (w_bf16 << 16) | src_slot. Produces rb[node*8+band] boundaries so the
// banded aggregation gets exact per-(row, src-band) segments. No serial sort.
__device__ void bucket_sort_body(int b, const uint2* __restrict__ earr,
                                 const int* __restrict__ boff, int* __restrict__ rb,
                                 unsigned int* __restrict__ edata, int N) {
    int s = boff[b], e = boff[b + 1];
    __shared__ int cnt[2048], off[2048], ts[256];
    int tid = threadIdx.x;
#pragma unroll
    for (int k = 0; k < 8; ++k) cnt[tid * 8 + k] = 0;
    __syncthreads();
    for (int i = s + tid; i < e; i += 256) {
        unsigned int xx = earr[i].x;
        int key = (((xx >> 16) & 255) << 3) | ((xx & 0xffffu) >> 13);
        atomicAdd(&cnt[key], 1);
    }
    __syncthreads();
    int run = 0;
#pragma unroll
    for (int k = 0; k < 8; ++k) { off[tid * 8 + k] = run; run += cnt[tid * 8 + k]; }
    ts[tid] = run;
    __syncthreads();
    int own = ts[tid];
    for (int d = 1; d < 256; d <<= 1) {
        int v = (tid >= d) ? ts[tid - d] : 0;
        __syncthreads();
        ts[tid] += v;
        __syncthreads();
    }
    int texcl = ts[tid] - own;
#pragma unroll
    for (int k = 0; k < 8; ++k) off[tid * 8 + k] += texcl;
    __syncthreads();
    // thread tid owns row tid of this bucket: write its 8 band starts
    int node = b * 256 + tid;
    if (node < N) {
#pragma unroll
        for (int k = 0; k < 8; ++k) rb[(size_t)node * 8 + k] = s + off[tid * 8 + k];
    }
    __syncthreads();
    for (int i = s + tid; i < e; i += 256) {
        uint2 r = earr[i];
        unsigned int xx = r.x;
        int key = (((xx >> 16) & 255) << 3) | ((xx & 0xffffu) >> 13);
        int k = atomicAdd(&off[key], 1);
        edata[s + k] = (f2bf_bits(__uint_as_float(r.y)) << 16) | (xx & 0xffffu);
    }
}

// ------- proj 256-out body: dense 64 slots x 256 outs per block, half-split I/O -------
__device__ void proj256_body(int gb,
                             const unsigned short* __restrict__ actLo,
                             const unsigned short* __restrict__ actHi,
                             const unsigned short* __restrict__ Wswz,
                             const int* __restrict__ lstart,
                             unsigned short* __restrict__ supLo,
                             unsigned short* __restrict__ supHi) {
    int warp = threadIdx.x >> 6;
    int lane = threadIdx.x & 63;
    int m0 = gb * 64;
    int lab = (m0 >= lstart[1]) + (m0 >= lstart[2]) + (m0 >= lstart[3]);
    int q = lane >> 4, c = lane & 15;
    int n0 = warp * 64;

    const unsigned short* aLo = actLo + (size_t)(m0 + c) * 128 + q * 8;
    const unsigned short* aHi = actHi + (size_t)(m0 + c) * 128 + q * 8;
    const unsigned short* bb = Wswz + (size_t)lab * FEAT * 256 + (size_t)(n0 + c) * 32 + q * 8;

    f32x4 acc[4][4] = {};
#pragma unroll
    for (int k0 = 0; k0 < 8; ++k0) {
        const unsigned short* abase = (k0 < 4) ? aLo : aHi;
        int koff = (k0 & 3) * 32;
        bf16x8 a[4];
#pragma unroll
        for (int t = 0; t < 4; ++t) a[t] = *(const bf16x8*)(abase + (size_t)t * 2048 + koff);
        const unsigned short* bk = bb + (size_t)k0 * 32 * 256;
#pragma unroll
        for (int u = 0; u < 4; ++u) {
            bf16x8 bfrag = *(const bf16x8*)(bk + u * 512);
#pragma unroll
            for (int t = 0; t < 4; ++t)
                acc[t][u] = __builtin_amdgcn_mfma_f32_16x16x32_bf16(a[t], bfrag, acc[t][u], 0, 0, 0);
        }
    }
    // pi-store: row = m0+t*16+q*4+r ; lane writes p = n0 + c*4 + u -> half n0>>7
    uint2* ov = (uint2*)((n0 >= 128) ? supHi : supLo);
    int cix = ((n0 & 64) >> 2) + c;
#pragma unroll
    for (int t = 0; t < 4; ++t) {
#pragma unroll
        for (int r = 0; r < 4; ++r) {
            int row = m0 + t * 16 + q * 4 + r;
            unsigned int lo = f2bf_bits(acc[t][0][r]) | (f2bf_bits(acc[t][1][r]) << 16);
            unsigned int hi = f2bf_bits(acc[t][2][r]) | (f2bf_bits(acc[t][3][r]) << 16);
            ov[(size_t)row * 32 + cix] = make_uint2(lo, hi);
        }
    }
}

// ================= FUSE_B: bucket_sort (blocks [0,NB)) + proj256 L1 (rest) =================
__global__ __launch_bounds__(256) void fuse_b(
    const uint2* __restrict__ earr, const int* __restrict__ boff,
    int* __restrict__ rb, unsigned int* __restrict__ edata, int N, int NB,
    const unsigned short* __restrict__ actLo, const unsigned short* __restrict__ actHi,
    const unsigned short* __restrict__ Wswz, const int* __restrict__ lstart,
    unsigned short* __restrict__ supLo, unsigned short* __restrict__ supHi) {
    int blk = (int)blockIdx.x;
    if (blk < NB) bucket_sort_body(blk, earr, boff, rb, edata, N);
    else proj256_body(blk - NB, actLo, actHi, Wswz, lstart, supLo, supHi);
}

// ---------------- standalone proj 256 (layer 2) ----------------
__global__ __launch_bounds__(256) void proj256_kernel(
    const unsigned short* __restrict__ actLo, const unsigned short* __restrict__ actHi,
    const unsigned short* __restrict__ Wswz, const int* __restrict__ lstart,
    unsigned short* __restrict__ supLo, unsigned short* __restrict__ supHi) {
    proj256_body((int)blockIdx.x, actLo, actHi, Wswz, lstart, supLo, supHi);
}

// ---------------- proj 64-out: dense 64 slots x 64 outs per block, half-split input ------
__global__ __launch_bounds__(256) void proj64_kernel(
    const unsigned short* __restrict__ actLo, const unsigned short* __restrict__ actHi,
    const unsigned short* __restrict__ Wswz, const int* __restrict__ lstart,
    unsigned short* __restrict__ outp) {
    int warp = threadIdx.x >> 6;
    int lane = threadIdx.x & 63;
    int m0 = blockIdx.x * 64;
    int lab = (m0 >= lstart[1]) + (m0 >= lstart[2]) + (m0 >= lstart[3]);
    int q = lane >> 4, c = lane & 15;
    int mb = m0 + warp * 16;

    const unsigned short* aLo = actLo + (size_t)(mb + c) * 128 + q * 8;
    const unsigned short* aHi = actHi + (size_t)(mb + c) * 128 + q * 8;
    const unsigned short* bb = Wswz + (size_t)lab * FEAT * OUT3 + (size_t)c * 32 + q * 8;

    f32x4 acc[4] = {};
#pragma unroll
    for (int k0 = 0; k0 < 8; ++k0) {
        const unsigned short* abase = (k0 < 4) ? aLo : aHi;
        bf16x8 a = *(const bf16x8*)(abase + (k0 & 3) * 32);
        const unsigned short* bk = bb + (size_t)k0 * 32 * OUT3;
#pragma unroll
        for (int u = 0; u < 4; ++u) {
            bf16x8 bfrag = *(const bf16x8*)(bk + u * 512);
            acc[u] = __builtin_amdgcn_mfma_f32_16x16x32_bf16(a, bfrag, acc[u], 0, 0, 0);
        }
    }
    uint2* ov = (uint2*)outp;
#pragma unroll
    for (int r = 0; r < 4; ++r) {
        int row = mb + q * 4 + r;
        unsigned int lo = f2bf_bits(acc[0][r]) | (f2bf_bits(acc[1][r]) << 16);
        unsigned int hi = f2bf_bits(acc[2][r]) | (f2bf_bits(acc[3][r]) << 16);
        ov[(size_t)row * 16 + c] = make_uint2(lo, hi);
    }
}

// ------- BANDED aggregation over ONE feature half (128 feats) -------
// All-resident grid (4 waves/block x 4 blocks/CU). Each wave owns NPW consecutive nodes;
// outer loop over NBAND src bands (8192 slots = 2MB half-table window, L2-resident since
// all resident waves sweep bands together). Within a band: NPW row-cursors advance in
// lockstep rounds -> NPW independent gathers in flight (branchless, select-masked).
__global__ __launch_bounds__(256, 4) void agg256hb_kernel(
    const unsigned int* __restrict__ sup, const int* __restrict__ rb,
    const unsigned int* __restrict__ edata, const int* __restrict__ iperm,
    const float* __restrict__ biasHalf, unsigned int* __restrict__ outp, int N) {
    int wid = (int)blockIdx.x * 4 + (int)(threadIdx.x >> 6);
    int lane = threadIdx.x & 63;
    int n0 = wid * NPW;
    if (n0 >= N) return;
    int cur[NPW];
    float a0[NPW], a1[NPW];
#pragma unroll
    for (int t = 0; t < NPW; ++t) {
        int n = n0 + t;
        cur[t] = (n < N) ? rb[(size_t)n * 8] : 0;
        a0[t] = 0.f; a1[t] = 0.f;
    }
#pragma unroll
    for (int sl = 1; sl <= NBAND; ++sl) {
        int nxt[NPW];
#pragma unroll
        for (int t = 0; t < NPW; ++t) {
            int n = n0 + t;
            nxt[t] = (n < N) ? rb[(size_t)n * 8 + sl] : 0;
        }
        bool any = true;
        while (any) {
            unsigned int ed[NPW], v[NPW];
#pragma unroll
            for (int t = 0; t < NPW; ++t) {
                int idx = (cur[t] < nxt[t]) ? cur[t] : 0;
                ed[t] = edata[idx];
            }
            __builtin_amdgcn_sched_barrier(0);
#pragma unroll
            for (int t = 0; t < NPW; ++t)
                v[t] = sup[(size_t)(ed[t] & 0xffffu) * 64 + lane];
            __builtin_amdgcn_sched_barrier(0);
            any = false;
#pragma unroll
            for (int t = 0; t < NPW; ++t) {
                bool act = cur[t] < nxt[t];
                float w = act ? __uint_as_float(ed[t] & 0xffff0000u) : 0.f;
                a0[t] += w * bfl(v[t]);
                a1[t] += w * bfh(v[t]);
                cur[t] += act ? 1 : 0;
                any = any || (cur[t] < nxt[t]);
            }
        }
    }
    float2 b = ((const float2*)biasHalf)[lane];
#pragma unroll
    for (int t = 0; t < NPW; ++t) {
        int n = n0 + t;
        if (n < N) {
            int slot = __builtin_amdgcn_readfirstlane(iperm[n]);
            float r0 = fmaxf(a0[t] + b.x, 0.f);
            float r1 = fmaxf(a1[t] + b.y, 0.f);
            unsigned int o = f2bf_bits(r0) | (f2bf_bits(r1) << 16);
            // output never re-read here: nontemporal keeps the gather window in L2
            __builtin_nontemporal_store(o, &outp[(size_t)slot * 64 + lane]);
        }
    }
}

// ---------------- aggregation, 64-feat: one wave per node (lane = stored pos), fp32 out --
__global__ __launch_bounds__(256) void agg64_kernel(
    const unsigned short* __restrict__ sup, const int* __restrict__ rb,
    const unsigned int* __restrict__ edata, const float* __restrict__ b3,
    float* __restrict__ outp, int N) {
    int warp = __builtin_amdgcn_readfirstlane((int)(threadIdx.x >> 6));
    int node = (int)blockIdx.x * 4 + warp;
    if (node >= N) return;
    int lane = threadIdx.x & 63;
    int s = __builtin_amdgcn_readfirstlane(rb[(size_t)node * 8]);
    int e = __builtin_amdgcn_readfirstlane(rb[(size_t)node * 8 + 8]);
    float a = 0.f;
    int j = s;
    for (; j + 16 <= e; j += 16) {
        unsigned int ed[16]; unsigned short v[16];
#pragma unroll
        for (int u = 0; u < 16; ++u) ed[u] = edata[j + u];
#pragma unroll
        for (int u = 0; u < 16; ++u) v[u] = sup[(size_t)(ed[u] & 0xffff) * 64 + lane];
#pragma unroll
        for (int u = 0; u < 16; ++u)
            a += __uint_as_float(ed[u] & 0xffff0000u) * __uint_as_float((unsigned int)v[u] << 16);
    }
    if (j < e) {
        unsigned int ed[16]; float wm[16]; unsigned short v[16];
#pragma unroll
        for (int u = 0; u < 16; ++u) {
            int jj = j + u;
            int jc = (jj < e) ? jj : e - 1;
            ed[u] = edata[jc];
            wm[u] = (jj < e) ? __uint_as_float(ed[u] & 0xffff0000u) : 0.f;
        }
#pragma unroll
        for (int u = 0; u < 16; ++u) v[u] = sup[(size_t)(ed[u] & 0xffff) * 64 + lane];
#pragma unroll
        for (int u = 0; u < 16; ++u)
            a += wm[u] * __uint_as_float((unsigned int)v[u] << 16);
    }
    int natp = (((lane & 3) << 4) | (lane >> 2));    // un-permute pi within the 64 outs
    outp[(size_t)node * 64 + natp] = a + b3[natp];
}

extern "C" void kernel_launch(void* const* d_in, const int* in_sizes, int n_in,
                              void* d_out, int out_size, void* d_ws, size_t ws_size,
                              hipStream_t stream) {
    const float* x        = (const float*)d_in[0];
    const int*   edge_src = (const int*)d_in[1];
    const int*   edge_dst = (const int*)d_in[2];
    const float* edge_w   = (const float*)d_in[3];
    const int*   labels   = (const int*)d_in[4];
    const float* W1 = (const float*)d_in[5];
    const float* b1 = (const float*)d_in[6];
    const float* W2 = (const float*)d_in[7];
    const float* b2 = (const float*)d_in[8];
    const float* W3 = (const float*)d_in[9];
    const float* b3 = (const float*)d_in[10];

    const int N = in_sizes[0] / FEAT;
    const int E = in_sizes[1];
    const int NB = (N + 255) >> 8;                    // dst buckets (orig id space)
    const int G64 = (N + NT * 64 + 63) / 64;          // slot-space 64-row tiles (upper bound)
    const int slotCap = G64 * 64;

    // ---- workspace carve (256B aligned) ----
    char* p = (char*)d_ws;
    auto alloc = [&](size_t bytes) -> char* {
        char* r = p;
        p += (bytes + 255) & ~(size_t)255;
        return r;
    };
    unsigned short* bufA = (unsigned short*)alloc((size_t)slotCap * FEAT * 2);
    unsigned short* bufB = (unsigned short*)alloc((size_t)slotCap * FEAT * 2);
    unsigned short* W1b  = (unsigned short*)alloc((size_t)NT * FEAT * FEAT * 2);
    unsigned short* W2b  = (unsigned short*)alloc((size_t)NT * FEAT * FEAT * 2);
    unsigned short* W3b  = (unsigned short*)alloc((size_t)NT * FEAT * OUT3 * 2);
    float*        biasPerm = (float*)alloc(512 * 4);
    int*          rb     = (int*)alloc(((size_t)N * NBAND + 8) * 4);
    unsigned int* edata  = (unsigned int*)alloc((size_t)E * 4);
    int*          iperm  = (int*)alloc((size_t)N * 4);
    int*          counters = (int*)alloc(264 * 4);    // bcnt[256] + lc[4] + lcur[4]
    int*          boff   = (int*)alloc(257 * 4);
    int*          gcur   = (int*)alloc(256 * 4);
    int*          lstart = (int*)alloc(64);
    int* bcnt = counters;
    int* lc   = counters + 256;
    int* lcur = counters + 260;

    // half-table views (lo = feats p<128, hi = p>=128), each slotCap*128 ushorts
    unsigned short* actLo = bufA;
    unsigned short* actHi = bufA + (size_t)slotCap * 128;
    unsigned short* supLo = bufB;
    unsigned short* supHi = bufB + (size_t)slotCap * 128;
    // bucket-sort staging ALIASED onto d_out (N*OUT3*4 = 12.8MB = E*8; d_out written
    // only by the final agg64, and earr is fully overwritten by scatter before reads)
    uint2* earr = (uint2*)d_out;

    const int nbEB = (E + 4095) / 4096;
    const int total4 = N * 64;                        // float4 groups in x
    const int nbX = (total4 + 511) / 512;
    const int totW = 2 * NT * FEAT * FEAT + NT * FEAT * OUT3 + 512;
    const int nbW = (totW + 511) / 512;

    // ---- CSR build + label-sort + casts ----
    hipMemsetAsync(counters, 0, 264 * 4, stream);
    pass_a<<<nbEB, 512, 0, stream>>>(edge_dst, labels, bcnt, lc, E, N);
    scan_master<<<1, 256, 0, stream>>>(bcnt, lc, boff, gcur, rb, lstart, NB, N, E);
    scatter_nodes<<<(N + 255) / 256, 256, 0, stream>>>(labels, lstart, lcur, iperm, N);
    fuse_a<<<nbEB + nbX + nbW, 512, 0, stream>>>(
        edge_src, edge_dst, edge_w, iperm, gcur, earr, E,
        x, actLo, actHi, total4,
        W1, W2, W3, b1, b2, W1b, W2b, W3b, biasPerm, nbEB, nbX);

    const int gridP = (N + 4 * NPW - 1) / (4 * NPW);  // all-resident banded-agg grid
    const int aggGrid = (N + 3) / 4;
    // ---- layer 1 (2048-bin band sort overlapped with proj256-L1) ----
    fuse_b<<<NB + G64, 256, 0, stream>>>(earr, boff, rb, edata, N, NB,
                                         actLo, actHi, W1b, lstart, supLo, supHi);
    agg256hb_kernel<<<gridP, 256, 0, stream>>>((const unsigned int*)supLo, rb, edata, iperm,
                                               biasPerm + 0, (unsigned int*)actLo, N);
    agg256hb_kernel<<<gridP, 256, 0, stream>>>((const unsigned int*)supHi, rb, edata, iperm,
                                               biasPerm + 128, (unsigned int*)actHi, N);
    // ---- layer 2 ----
    proj256_kernel<<<G64, 256, 0, stream>>>(actLo, actHi, W2b, lstart, supLo, supHi);
    agg256hb_kernel<<<gridP, 256, 0, stream>>>((const unsigned int*)supLo, rb, edata, iperm,
                                               biasPerm + 256, (unsigned int*)actLo, N);
    agg256hb_kernel<<<gridP, 256, 0, stream>>>((const unsigned int*)supHi, rb, edata, iperm,
                                               biasPerm + 384, (unsigned int*)actHi, N);
    // ---- layer 3 ----
    proj64_kernel<<<G64, 256, 0, stream>>>(actLo, actHi, W3b, lstart, bufB);
    agg64_kernel<<<aggGrid, 256, 0, stream>>>(bufB, rb, edata, b3, (float*)d_out, N);
}

// Round 8
// 475.081 us; speedup vs baseline: 13.6046x; 1.6160x over previous
//
#include <hip/hip_runtime.h>
#include <hip/hip_bf16.h>

#define NT 4           // node types (labels)
#define FEAT 256       // nfeat == nhid
#define OUT3 64        // nclass

typedef __bf16 bf16x8 __attribute__((ext_vector_type(8)));
typedef float  f32x4  __attribute__((ext_vector_type(4)));

__device__ inline unsigned int f2bf_bits(float f) {
    __hip_bfloat16 h = __float2bfloat16(f);   // RNE
    unsigned short u;
    __builtin_memcpy(&u, &h, 2);
    return (unsigned int)u;
}
__device__ inline float bfl(unsigned int u) { return __uint_as_float(u << 16); }
__device__ inline float bfh(unsigned int u) { return __uint_as_float(u & 0xffff0000u); }
// stored feature pos p (pi order) -> natural feature index, within each 64-block
__device__ __host__ inline int nat_of(int p) {
    int lo = p & 63;
    return (p & ~63) | (((lo & 3) << 4) | (lo >> 2));
}

// ---------------- pass A: dst-bucket histogram (dst>>8) + label histogram ----------------
__global__ __launch_bounds__(512) void pass_a(const int* __restrict__ dst,
                                              const int* __restrict__ labels,
                                              int* __restrict__ bcnt, int* __restrict__ lc,
                                              int E, int N) {
    __shared__ int h[256];
    __shared__ int lh[NT];
    int tid = threadIdx.x;
    if (tid < 256) h[tid] = 0;
    if (tid < NT) lh[tid] = 0;
    __syncthreads();
    int base = blockIdx.x * 4096;
#pragma unroll
    for (int k = 0; k < 8; ++k) {
        int e = base + k * 512 + tid;
        if (e < E) atomicAdd(&h[((unsigned)dst[e]) >> 8], 1);
    }
#pragma unroll
    for (int k = 0; k < 8; ++k) {
        int i = base + k * 512 + tid;
        if (i < N) atomicAdd(&lh[labels[i]], 1);
    }
    __syncthreads();
    if (tid < 256) { int v = h[tid]; if (v) atomicAdd(&bcnt[tid], v); }
    if (tid < NT) { int v = lh[tid]; if (v) atomicAdd(&lc[tid], v); }
}

// ------- scan buckets -> boff/gcur, rb[8N]=E; label starts (pad 64) -------
__global__ __launch_bounds__(256) void scan_master(
    const int* __restrict__ bcnt, const int* __restrict__ lc,
    int* __restrict__ boff, int* __restrict__ gcur, int* __restrict__ rb,
    int* __restrict__ lstart, int NB, int N, int E) {
    __shared__ int s[256];
    int tid = threadIdx.x;
    int own = (tid < NB) ? bcnt[tid] : 0;
    s[tid] = own;
    __syncthreads();
    for (int d = 1; d < 256; d <<= 1) {
        int v = (tid >= d) ? s[tid - d] : 0;
        __syncthreads();
        s[tid] += v;
        __syncthreads();
    }
    int excl = s[tid] - own;
    if (tid < NB) { boff[tid] = excl; gcur[tid] = excl; }
    if (tid == 0) {
        boff[NB] = E; rb[(size_t)N * 8] = E;
        int run = 0;
        for (int l = 0; l < NT; ++l) {
            lstart[l] = run;
            run += (lc[l] + 63) & ~63;
        }
    }
}

// ------- node scatter: build iperm (orig -> label-sorted slot) -------
__global__ void scatter_nodes(const int* __restrict__ labels, const int* __restrict__ lstart,
                              int* __restrict__ lcur, int* __restrict__ iperm, int N) {
    int n = blockIdx.x * 256 + threadIdx.x;
    int lab = (n < N) ? labels[n] : -1;
    int lane = threadIdx.x & 63;
    for (int l = 0; l < NT; ++l) {
        unsigned long long m = __ballot(lab == l);
        if (m == 0ull) continue;
        int leader = __builtin_ctzll(m);
        int base = 0;
        if (lane == leader) base = atomicAdd(&lcur[l], (int)__popcll(m));
        base = __shfl(base, leader, 64);
        if (lab == l) {
            int prefix = (int)__popcll(m & ((1ull << lane) - 1ull));
            iperm[n] = lstart[l] + base + prefix;
        }
    }
}

// ================= FUSE_A: scatter_edges + cast_x + cast_w_all =================
// seg 0 [0, nbEB): edge scatter into bucket regions; earr rec: x = slot|(dst&255)<<16, y = w
// seg 1 [nbEB, nbEB+nbX): cast x -> bf16 half-split slot rows
// seg 2 rest: cast W1/W2/W3 -> swizzled bf16 + permuted biases
__global__ __launch_bounds__(512) void fuse_a(
    const int* __restrict__ src, const int* __restrict__ dst, const float* __restrict__ w,
    const int* __restrict__ iperm, int* __restrict__ gcur, uint2* __restrict__ earr, int E,
    const float* __restrict__ x, unsigned short* __restrict__ actLo,
    unsigned short* __restrict__ actHi, int total4,
    const float* __restrict__ W1, const float* __restrict__ W2, const float* __restrict__ W3,
    const float* __restrict__ b1, const float* __restrict__ b2,
    unsigned short* __restrict__ W1b, unsigned short* __restrict__ W2b,
    unsigned short* __restrict__ W3b, float* __restrict__ biasPerm,
    int nbEB, int nbX) {
    int tid = threadIdx.x;
    int blk = (int)blockIdx.x;
    if (blk < nbEB) {
        // ---- edge scatter ----
        __shared__ int h[256];
        __shared__ int basearr[256];
        if (tid < 256) h[tid] = 0;
        __syncthreads();
        int base = blk * 4096;
        int b[8], rank[8], px[8]; float wv[8];
#pragma unroll
        for (int k = 0; k < 8; ++k) {
            int e = base + k * 512 + tid;
            if (e < E) {
                int d = dst[e];
                b[k] = ((unsigned)d) >> 8;
                px[k] = iperm[src[e]] | ((d & 255) << 16);
                wv[k] = w[e];
                rank[k] = atomicAdd(&h[b[k]], 1);
            } else b[k] = -1;
        }
        __syncthreads();
        if (tid < 256) { int c = h[tid]; basearr[tid] = c ? atomicAdd(&gcur[tid], c) : 0; }
        __syncthreads();
#pragma unroll
        for (int k = 0; k < 8; ++k) {
            if (b[k] >= 0) {
                int pos = basearr[b[k]] + rank[k];
                earr[pos] = make_uint2((unsigned)px[k], __float_as_uint(wv[k]));
            }
        }
    } else if (blk < nbEB + nbX) {
        // ---- cast x ----
        int i = (blk - nbEB) * 512 + tid;
        if (i < total4) {
            float4 v = ((const float4*)x)[i];
            unsigned int lo = f2bf_bits(v.x) | (f2bf_bits(v.y) << 16);
            unsigned int hi = f2bf_bits(v.z) | (f2bf_bits(v.w) << 16);
            int slot = iperm[i >> 6];
            unsigned short* dp = ((i & 63) >= 32) ? actHi : actLo;
            ((uint2*)dp)[(size_t)slot * 32 + (i & 31)] = make_uint2(lo, hi);
        }
    } else {
        // ---- cast W + biases ----
        const int S = NT * FEAT * FEAT;
        const int S3 = NT * FEAT * OUT3;
        int idx = (blk - nbEB - nbX) * 512 + tid;
        if (idx < 2 * S + S3) {
            const float* W; unsigned short* D; int OUTF; int t; bool remap;
            if (idx < S)          { W = W1; D = W1b; OUTF = FEAT; t = idx;         remap = false; }
            else if (idx < 2 * S) { W = W2; D = W2b; OUTF = FEAT; t = idx - S;     remap = true; }
            else                  { W = W3; D = W3b; OUTF = OUT3; t = idx - 2 * S; remap = true; }
            int n = t % OUTF;
            int r = t / OUTF;              // lab*256 + k_slot
            int j = r & 7, q = (r >> 3) & 3, k0 = (r >> 5) & 7, lab = r >> 8;
            int k_slot = k0 * 32 + q * 8 + j;
            int k_src = remap ? nat_of(k_slot) : k_slot;
            float f = W[((size_t)(lab * FEAT + k_src)) * OUTF + n];
            D[(((size_t)lab * 8 + k0) * OUTF + n) * 32 + q * 8 + j] = (unsigned short)f2bf_bits(f);
        } else {
            int p2 = idx - (2 * S + S3);
            if (p2 < 256) biasPerm[p2] = b1[nat_of(p2)];
            else if (p2 < 512) biasPerm[p2] = b2[nat_of(p2 - 256)];
        }
    }
}

// ------- bucket sort body (256 thr): 2048-bin counting sort by (dst_low8, src_band3) -----
// final record: (w_bf16 << 16) | src_slot. Rows contiguous, band-ascending within row
// (free intra-row phasing for the sequential walk). rb[node*8+k] = band starts.
__device__ void bucket_sort_body(int b, const uint2* __restrict__ earr,
                                 const int* __restrict__ boff, int* __restrict__ rb,
                                 unsigned int* __restrict__ edata, int N) {
    int s = boff[b], e = boff[b + 1];
    __shared__ int cnt[2048], off[2048], ts[256];
    int tid = threadIdx.x;
#pragma unroll
    for (int k = 0; k < 8; ++k) cnt[tid * 8 + k] = 0;
    __syncthreads();
    for (int i = s + tid; i < e; i += 256) {
        unsigned int xx = earr[i].x;
        int key = (((xx >> 16) & 255) << 3) | ((xx & 0xffffu) >> 13);
        atomicAdd(&cnt[key], 1);
    }
    __syncthreads();
    int run = 0;
#pragma unroll
    for (int k = 0; k < 8; ++k) { off[tid * 8 + k] = run; run += cnt[tid * 8 + k]; }
    ts[tid] = run;
    __syncthreads();
    int own = ts[tid];
    for (int d = 1; d < 256; d <<= 1) {
        int v = (tid >= d) ? ts[tid - d] : 0;
        __syncthreads();
        ts[tid] += v;
        __syncthreads();
    }
    int texcl = ts[tid] - own;
#pragma unroll
    for (int k = 0; k < 8; ++k) off[tid * 8 + k] += texcl;
    __syncthreads();
    int node = b * 256 + tid;
    if (node < N) {
#pragma unroll
        for (int k = 0; k < 8; ++k) rb[(size_t)node * 8 + k] = s + off[tid * 8 + k];
    }
    __syncthreads();
    for (int i = s + tid; i < e; i += 256) {
        uint2 r = earr[i];
        unsigned int xx = r.x;
        int key = (((xx >> 16) & 255) << 3) | ((xx & 0xffffu) >> 13);
        int k = atomicAdd(&off[key], 1);
        edata[s + k] = (f2bf_bits(__uint_as_float(r.y)) << 16) | (xx & 0xffffu);
    }
}

// ------- proj 256-out body: dense 64 slots x 256 outs per block, half-split I/O -------
__device__ void proj256_body(int gb,
                             const unsigned short* __restrict__ actLo,
                             const unsigned short* __restrict__ actHi,
                             const unsigned short* __restrict__ Wswz,
                             const int* __restrict__ lstart,
                             unsigned short* __restrict__ supLo,
                             unsigned short* __restrict__ supHi) {
    int warp = threadIdx.x >> 6;
    int lane = threadIdx.x & 63;
    int m0 = gb * 64;
    int lab = (m0 >= lstart[1]) + (m0 >= lstart[2]) + (m0 >= lstart[3]);
    int q = lane >> 4, c = lane & 15;
    int n0 = warp * 64;

    const unsigned short* aLo = actLo + (size_t)(m0 + c) * 128 + q * 8;
    const unsigned short* aHi = actHi + (size_t)(m0 + c) * 128 + q * 8;
    const unsigned short* bb = Wswz + (size_t)lab * FEAT * 256 + (size_t)(n0 + c) * 32 + q * 8;

    f32x4 acc[4][4] = {};
#pragma unroll
    for (int k0 = 0; k0 < 8; ++k0) {
        const unsigned short* abase = (k0 < 4) ? aLo : aHi;
        int koff = (k0 & 3) * 32;
        bf16x8 a[4];
#pragma unroll
        for (int t = 0; t < 4; ++t) a[t] = *(const bf16x8*)(abase + (size_t)t * 2048 + koff);
        const unsigned short* bk = bb + (size_t)k0 * 32 * 256;
#pragma unroll
        for (int u = 0; u < 4; ++u) {
            bf16x8 bfrag = *(const bf16x8*)(bk + u * 512);
#pragma unroll
            for (int t = 0; t < 4; ++t)
                acc[t][u] = __builtin_amdgcn_mfma_f32_16x16x32_bf16(a[t], bfrag, acc[t][u], 0, 0, 0);
        }
    }
    // pi-store: row = m0+t*16+q*4+r ; lane writes p = n0 + c*4 + u -> half n0>>7
    uint2* ov = (uint2*)((n0 >= 128) ? supHi : supLo);
    int cix = ((n0 & 64) >> 2) + c;
#pragma unroll
    for (int t = 0; t < 4; ++t) {
#pragma unroll
        for (int r = 0; r < 4; ++r) {
            int row = m0 + t * 16 + q * 4 + r;
            unsigned int lo = f2bf_bits(acc[t][0][r]) | (f2bf_bits(acc[t][1][r]) << 16);
            unsigned int hi = f2bf_bits(acc[t][2][r]) | (f2bf_bits(acc[t][3][r]) << 16);
            ov[(size_t)row * 32 + cix] = make_uint2(lo, hi);
        }
    }
}

// ================= FUSE_B: bucket_sort (blocks [0,NB)) + proj256 L1 (rest) =================
__global__ __launch_bounds__(256) void fuse_b(
    const uint2* __restrict__ earr, const int* __restrict__ boff,
    int* __restrict__ rb, unsigned int* __restrict__ edata, int N, int NB,
    const unsigned short* __restrict__ actLo, const unsigned short* __restrict__ actHi,
    const unsigned short* __restrict__ Wswz, const int* __restrict__ lstart,
    unsigned short* __restrict__ supLo, unsigned short* __restrict__ supHi) {
    int blk = (int)blockIdx.x;
    if (blk < NB) bucket_sort_body(blk, earr, boff, rb, edata, N);
    else proj256_body(blk - NB, actLo, actHi, Wswz, lstart, supLo, supHi);
}

// ---------------- standalone proj 256 (layer 2) ----------------
__global__ __launch_bounds__(256) void proj256_kernel(
    const unsigned short* __restrict__ actLo, const unsigned short* __restrict__ actHi,
    const unsigned short* __restrict__ Wswz, const int* __restrict__ lstart,
    unsigned short* __restrict__ supLo, unsigned short* __restrict__ supHi) {
    proj256_body((int)blockIdx.x, actLo, actHi, Wswz, lstart, supLo, supHi);
}

// ---------------- proj 64-out: dense 64 slots x 64 outs per block, half-split input ------
__global__ __launch_bounds__(256) void proj64_kernel(
    const unsigned short* __restrict__ actLo, const unsigned short* __restrict__ actHi,
    const unsigned short* __restrict__ Wswz, const int* __restrict__ lstart,
    unsigned short* __restrict__ outp) {
    int warp = threadIdx.x >> 6;
    int lane = threadIdx.x & 63;
    int m0 = blockIdx.x * 64;
    int lab = (m0 >= lstart[1]) + (m0 >= lstart[2]) + (m0 >= lstart[3]);
    int q = lane >> 4, c = lane & 15;
    int mb = m0 + warp * 16;

    const unsigned short* aLo = actLo + (size_t)(mb + c) * 128 + q * 8;
    const unsigned short* aHi = actHi + (size_t)(mb + c) * 128 + q * 8;
    const unsigned short* bb = Wswz + (size_t)lab * FEAT * OUT3 + (size_t)c * 32 + q * 8;

    f32x4 acc[4] = {};
#pragma unroll
    for (int k0 = 0; k0 < 8; ++k0) {
        const unsigned short* abase = (k0 < 4) ? aLo : aHi;
        bf16x8 a = *(const bf16x8*)(abase + (k0 & 3) * 32);
        const unsigned short* bk = bb + (size_t)k0 * 32 * OUT3;
#pragma unroll
        for (int u = 0; u < 4; ++u) {
            bf16x8 bfrag = *(const bf16x8*)(bk + u * 512);
            acc[u] = __builtin_amdgcn_mfma_f32_16x16x32_bf16(a, bfrag, acc[u], 0, 0, 0);
        }
    }
    uint2* ov = (uint2*)outp;
#pragma unroll
    for (int r = 0; r < 4; ++r) {
        int row = mb + q * 4 + r;
        unsigned int lo = f2bf_bits(acc[0][r]) | (f2bf_bits(acc[1][r]) << 16);
        unsigned int hi = f2bf_bits(acc[2][r]) | (f2bf_bits(acc[3][r]) << 16);
        ov[(size_t)row * 16 + c] = make_uint2(lo, hi);
    }
}

// ------- XCD-parity half-split aggregation (128 feats per block) -------
// Block parity selects the feature half; round-robin blockIdx->XCD dispatch then puts
// Lo on even XCDs and Hi on odd XCDs, halving each XCD's compulsory L2-miss traffic
// (each L2 sweeps one 12.8MB half instead of both). Body = proven batch-16 walk;
// edata is band-sorted within each row so co-progressing waves share a src window.
__global__ __launch_bounds__(256) void agg256x_kernel(
    const unsigned int* __restrict__ supLo, const unsigned int* __restrict__ supHi,
    const int* __restrict__ rb, const unsigned int* __restrict__ edata,
    const int* __restrict__ iperm, const float* __restrict__ biasPerm, int bOff,
    unsigned int* __restrict__ outLo, unsigned int* __restrict__ outHi, int N) {
    int blk = (int)blockIdx.x;
    int half = blk & 1;
    int warp = __builtin_amdgcn_readfirstlane((int)(threadIdx.x >> 6));
    int node = (blk >> 1) * 4 + warp;
    if (node >= N) return;
    int lane = threadIdx.x & 63;
    const unsigned int* sup = half ? supHi : supLo;
    unsigned int* outp = half ? outHi : outLo;
    int s = __builtin_amdgcn_readfirstlane(rb[(size_t)node * 8]);
    int e = __builtin_amdgcn_readfirstlane(rb[(size_t)node * 8 + 8]);
    int slot = __builtin_amdgcn_readfirstlane(iperm[node]);
    float a0 = 0.f, a1 = 0.f;
    int j = s;
    for (; j + 16 <= e; j += 16) {
        unsigned int ed[16], v[16];
#pragma unroll
        for (int u = 0; u < 16; ++u) ed[u] = edata[j + u];
        __builtin_amdgcn_sched_barrier(0);
#pragma unroll
        for (int u = 0; u < 16; ++u) v[u] = sup[(size_t)(ed[u] & 0xffff) * 64 + lane];
        __builtin_amdgcn_sched_barrier(0);
#pragma unroll
        for (int u = 0; u < 16; ++u) {
            float w = __uint_as_float(ed[u] & 0xffff0000u);
            a0 += w * bfl(v[u]); a1 += w * bfh(v[u]);
        }
    }
    if (j < e) {   // masked tail (<=15 real edges)
        unsigned int ed[16], v[16]; float wm[16];
#pragma unroll
        for (int u = 0; u < 16; ++u) {
            int jj = j + u;
            int jc = (jj < e) ? jj : e - 1;
            ed[u] = edata[jc];
            wm[u] = (jj < e) ? __uint_as_float(ed[u] & 0xffff0000u) : 0.f;
        }
        __builtin_amdgcn_sched_barrier(0);
#pragma unroll
        for (int u = 0; u < 16; ++u) v[u] = sup[(size_t)(ed[u] & 0xffff) * 64 + lane];
        __builtin_amdgcn_sched_barrier(0);
#pragma unroll
        for (int u = 0; u < 16; ++u) { a0 += wm[u] * bfl(v[u]); a1 += wm[u] * bfh(v[u]); }
    }
    float2 b = ((const float2*)(biasPerm + bOff + half * 128))[lane];
    a0 = fmaxf(a0 + b.x, 0.f);
    a1 = fmaxf(a1 + b.y, 0.f);
    unsigned int o = f2bf_bits(a0) | (f2bf_bits(a1) << 16);
    // output never re-read here: nontemporal keeps the sup window resident in L2
    __builtin_nontemporal_store(o, &outp[(size_t)slot * 64 + lane]);
}

// ---------------- aggregation, 64-feat: one wave per node (lane = stored pos), fp32 out --
__global__ __launch_bounds__(256) void agg64_kernel(
    const unsigned short* __restrict__ sup, const int* __restrict__ rb,
    const unsigned int* __restrict__ edata, const float* __restrict__ b3,
    float* __restrict__ outp, int N) {
    int warp = __builtin_amdgcn_readfirstlane((int)(threadIdx.x >> 6));
    int node = (int)blockIdx.x * 4 + warp;
    if (node >= N) return;
    int lane = threadIdx.x & 63;
    int s = __builtin_amdgcn_readfirstlane(rb[(size_t)node * 8]);
    int e = __builtin_amdgcn_readfirstlane(rb[(size_t)node * 8 + 8]);
    float a = 0.f;
    int j = s;
    for (; j + 16 <= e; j += 16) {
        unsigned int ed[16]; unsigned short v[16];
#pragma unroll
        for (int u = 0; u < 16; ++u) ed[u] = edata[j + u];
#pragma unroll
        for (int u = 0; u < 16; ++u) v[u] = sup[(size_t)(ed[u] & 0xffff) * 64 + lane];
#pragma unroll
        for (int u = 0; u < 16; ++u)
            a += __uint_as_float(ed[u] & 0xffff0000u) * __uint_as_float((unsigned int)v[u] << 16);
    }
    if (j < e) {
        unsigned int ed[16]; float wm[16]; unsigned short v[16];
#pragma unroll
        for (int u = 0; u < 16; ++u) {
            int jj = j + u;
            int jc = (jj < e) ? jj : e - 1;
            ed[u] = edata[jc];
            wm[u] = (jj < e) ? __uint_as_float(ed[u] & 0xffff0000u) : 0.f;
        }
#pragma unroll
        for (int u = 0; u < 16; ++u) v[u] = sup[(size_t)(ed[u] & 0xffff) * 64 + lane];
#pragma unroll
        for (int u = 0; u < 16; ++u)
            a += wm[u] * __uint_as_float((unsigned int)v[u] << 16);
    }
    int natp = (((lane & 3) << 4) | (lane >> 2));    // un-permute pi within the 64 outs
    outp[(size_t)node * 64 + natp] = a + b3[natp];
}

extern "C" void kernel_launch(void* const* d_in, const int* in_sizes, int n_in,
                              void* d_out, int out_size, void* d_ws, size_t ws_size,
                              hipStream_t stream) {
    const float* x        = (const float*)d_in[0];
    const int*   edge_src = (const int*)d_in[1];
    const int*   edge_dst = (const int*)d_in[2];
    const float* edge_w   = (const float*)d_in[3];
    const int*   labels   = (const int*)d_in[4];
    const float* W1 = (const float*)d_in[5];
    const float* b1 = (const float*)d_in[6];
    const float* W2 = (const float*)d_in[7];
    const float* b2 = (const float*)d_in[8];
    const float* W3 = (const float*)d_in[9];
    const float* b3 = (const float*)d_in[10];

    const int N = in_sizes[0] / FEAT;
    const int E = in_sizes[1];
    const int NB = (N + 255) >> 8;                    // dst buckets (orig id space)
    const int G64 = (N + NT * 64 + 63) / 64;          // slot-space 64-row tiles (upper bound)
    const int slotCap = G64 * 64;

    // ---- workspace carve (256B aligned) ----
    char* p = (char*)d_ws;
    auto alloc = [&](size_t bytes) -> char* {
        char* r = p;
        p += (bytes + 255) & ~(size_t)255;
        return r;
    };
    unsigned short* bufA = (unsigned short*)alloc((size_t)slotCap * FEAT * 2);
    unsigned short* bufB = (unsigned short*)alloc((size_t)slotCap * FEAT * 2);
    unsigned short* W1b  = (unsigned short*)alloc((size_t)NT * FEAT * FEAT * 2);
    unsigned short* W2b  = (unsigned short*)alloc((size_t)NT * FEAT * FEAT * 2);
    unsigned short* W3b  = (unsigned short*)alloc((size_t)NT * FEAT * OUT3 * 2);
    float*        biasPerm = (float*)alloc(512 * 4);
    int*          rb     = (int*)alloc(((size_t)N * 8 + 8) * 4);
    unsigned int* edata  = (unsigned int*)alloc((size_t)E * 4);
    int*          iperm  = (int*)alloc((size_t)N * 4);
    int*          counters = (int*)alloc(264 * 4);    // bcnt[256] + lc[4] + lcur[4]
    int*          boff   = (int*)alloc(257 * 4);
    int*          gcur   = (int*)alloc(256 * 4);
    int*          lstart = (int*)alloc(64);
    int* bcnt = counters;
    int* lc   = counters + 256;
    int* lcur = counters + 260;

    // half-table views (lo = feats p<128, hi = p>=128), each slotCap*128 ushorts
    unsigned short* actLo = bufA;
    unsigned short* actHi = bufA + (size_t)slotCap * 128;
    unsigned short* supLo = bufB;
    unsigned short* supHi = bufB + (size_t)slotCap * 128;
    // bucket-sort staging ALIASED onto d_out (N*OUT3*4 = 12.8MB = E*8; d_out written
    // only by the final agg64, and earr is fully overwritten by scatter before reads)
    uint2* earr = (uint2*)d_out;

    const int nbEB = (E + 4095) / 4096;
    const int total4 = N * 64;                        // float4 groups in x
    const int nbX = (total4 + 511) / 512;
    const int totW = 2 * NT * FEAT * FEAT + NT * FEAT * OUT3 + 512;
    const int nbW = (totW + 511) / 512;

    // ---- CSR build + label-sort + casts ----
    hipMemsetAsync(counters, 0, 264 * 4, stream);
    pass_a<<<nbEB, 512, 0, stream>>>(edge_dst, labels, bcnt, lc, E, N);
    scan_master<<<1, 256, 0, stream>>>(bcnt, lc, boff, gcur, rb, lstart, NB, N, E);
    scatter_nodes<<<(N + 255) / 256, 256, 0, stream>>>(labels, lstart, lcur, iperm, N);
    fuse_a<<<nbEB + nbX + nbW, 512, 0, stream>>>(
        edge_src, edge_dst, edge_w, iperm, gcur, earr, E,
        x, actLo, actHi, total4,
        W1, W2, W3, b1, b2, W1b, W2b, W3b, biasPerm, nbEB, nbX);

    const int aggGrid = (N + 3) / 4;
    // ---- layer 1 (band sort overlapped with proj256-L1) ----
    fuse_b<<<NB + G64, 256, 0, stream>>>(earr, boff, rb, edata, N, NB,
                                         actLo, actHi, W1b, lstart, supLo, supHi);
    agg256x_kernel<<<2 * aggGrid, 256, 0, stream>>>(
        (const unsigned int*)supLo, (const unsigned int*)supHi, rb, edata, iperm,
        biasPerm, 0, (unsigned int*)actLo, (unsigned int*)actHi, N);
    // ---- layer 2 ----
    proj256_kernel<<<G64, 256, 0, stream>>>(actLo, actHi, W2b, lstart, supLo, supHi);
    agg256x_kernel<<<2 * aggGrid, 256, 0, stream>>>(
        (const unsigned int*)supLo, (const unsigned int*)supHi, rb, edata, iperm,
        biasPerm, 256, (unsigned int*)actLo, (unsigned int*)actHi, N);
    // ---- layer 3 ----
    proj64_kernel<<<G64, 256, 0, stream>>>(actLo, actHi, W3b, lstart, bufB);
    agg64_kernel<<<aggGrid, 256, 0, stream>>>(bufB, rb, edata, b3, (float*)d_out, N);
}